// Round 12
// baseline (271.709 us; speedup 1.0000x reference)
//
#include <hip/hip_runtime.h>

// ---------------- problem constants ----------------
constexpr int B_ = 256;        // batch
constexpr int K_ = 6144;       // block length
constexpr int NITER = 6;
constexpr int L_ = 8;          // window valid length -> C_=768 = 3 blocks/CU
constexpr int W0_ = 32;        // uniform-init warmup (iteration 0)
constexpr int C_ = K_ / L_;    // chunks = 768
constexpr float LOG2E = 1.4426950408889634f;
constexpr float LN2   = 0.6931471805599453f;

static_assert(K_ % L_ == 0, "");
static_assert((L_ % 2) == 0 && (W0_ % 2) == 0, "");

#if __has_builtin(__builtin_amdgcn_exp2f)
#define EXP2F(x) __builtin_amdgcn_exp2f(x)
#else
#define EXP2F(x) exp2f(x)
#endif
#if __has_builtin(__builtin_amdgcn_logf)
#define LOG2F(x) __builtin_amdgcn_logf(x)
#else
#define LOG2F(x) log2f(x)
#endif
#if __has_builtin(__builtin_amdgcn_rcpf)
#define RCPF(x) __builtin_amdgcn_rcpf(x)
#else
#define RCPF(x) (1.0f / (x))
#endif

// ---- bf16 scalar helpers (RNE) ----
__device__ __forceinline__ float b2f(unsigned short u) {
  return __uint_as_float((unsigned)u << 16);
}
__device__ __forceinline__ unsigned short f2b(float f) {
  unsigned u = __float_as_uint(f);
  u += 0x7FFFu + ((u >> 16) & 1u);
  return (unsigned short)(u >> 16);
}

// trellis: fb(s,u)=u^s1^s0, nxt(s,u)=(fb<<2)|(s>>1), par(s,u)=u^s1^s2
// Linear-domain with normalized gammas: ghat[u][p] = A_u*B_p, A={1,es} by
// sign of gx (es=2^-|gx|), B likewise (ep=2^-|gy|). Common scale cancels in
// the posterior ratio and renormalized alpha/beta -> equivalent to log-MAP.

__device__ __forceinline__ void gam_lin(float gxv, float gyv, float g[4]) {
  float es = EXP2F(-fabsf(gxv));
  float ep = EXP2F(-fabsf(gyv));
  float fu0 = gxv >= 0.0f ? 1.0f : es;
  float fu1 = gxv >= 0.0f ? es : 1.0f;
  float fp0 = gyv >= 0.0f ? 1.0f : ep;
  float fp1 = gyv >= 0.0f ? ep : 1.0f;
  g[0] = fu0 * fp0; g[1] = fu0 * fp1;
  g[2] = fu1 * fp0; g[3] = fu1 * fp1;
}

__device__ __forceinline__ void step_fwd_lin(float a[8], const float g[4]) {
  float an[8];
#pragma unroll
  for (int sn = 0; sn < 8; ++sn) {
    const int u0 = ((sn >> 2) ^ (sn & 1)) & 1;
    const int p0 = ((sn >> 2) ^ ((sn >> 1) & 1)) & 1;
    an[sn] = a[(sn & 3) * 2] * g[u0 * 2 + p0]
           + a[(sn & 3) * 2 + 1] * g[(u0 ^ 1) * 2 + (p0 ^ 1)];
  }
#pragma unroll
  for (int s = 0; s < 8; ++s) a[s] = an[s];
}

__device__ __forceinline__ void step_bwd_lin(float bt[8], const float g[4]) {
  float bn[8];
#pragma unroll
  for (int s = 0; s < 8; ++s) {
    const int s0 = s & 1, s1b = (s >> 1) & 1, s2b = (s >> 2) & 1;
    const int f0 = s1b ^ s0, q = s1b ^ s2b;
    bn[s] = g[q] * bt[(f0 << 2) | (s >> 1)]
          + g[2 + (q ^ 1)] * bt[((f0 ^ 1) << 2) | (s >> 1)];
  }
#pragma unroll
  for (int s = 0; s < 8; ++s) bt[s] = bn[s];
}

// max-renorm with tiny floor injection: NaN/underflow-proof
__device__ __forceinline__ void renorm_lin(float a[8]) {
  float m = fmaxf(fmaxf(fmaxf(a[0], a[1]), fmaxf(a[2], a[3])),
                  fmaxf(fmaxf(a[4], a[5]), fmaxf(a[6], a[7])));
  float r = RCPF(fmaxf(m, 1e-30f));
#pragma unroll
  for (int s = 0; s < 8; ++s) a[s] = fmaf(a[s], r, 1e-32f);
}

// ---- bf16-packed boundary states (renormalized probs in [1e-32,1]) ------
__device__ __forceinline__ void store8_bf16(unsigned short* p, const float a[8]) {
  unsigned int us[8];
#pragma unroll
  for (int s = 0; s < 8; ++s) us[s] = f2b(a[s]);
  uint4 v;
  v.x = us[0] | (us[1] << 16);
  v.y = us[2] | (us[3] << 16);
  v.z = us[4] | (us[5] << 16);
  v.w = us[6] | (us[7] << 16);
  *(uint4*)p = v;
}

__device__ __forceinline__ void unpack8_bf16(uint4 v, float a[8]) {
  a[0] = __uint_as_float(v.x << 16);
  a[1] = __uint_as_float(v.x & 0xFFFF0000u);
  a[2] = __uint_as_float(v.y << 16);
  a[3] = __uint_as_float(v.y & 0xFFFF0000u);
  a[4] = __uint_as_float(v.z << 16);
  a[5] = __uint_as_float(v.z & 0xFFFF0000u);
  a[6] = __uint_as_float(v.w << 16);
  a[7] = __uint_as_float(v.w & 0xFFFF0000u);
}

// ---------------- k_half: one windowed BCJR half-iteration (linear) -------
// 256-thread blocks = 4 waves = the 4 b-quarters of ONE chunk.
// gy planes are bf16 (parity LLR only feeds exp2 -> 0.4% rel error, benign).
// wmode 0: uniform warmup W0 (it 0); wmode 2: pure inheritance (it>=1).
// S[c] = alpha at c*L_ (bf16, renormed); T[c] = beta at c*L_.
// mode 0: scatter extrinsic into other decoder's gx.  mode 1: write lpost.
// wrS 0: skip dead boundary-state stores (last iteration).
__global__ __launch_bounds__(256, 4) void k_half(const float* __restrict__ gx,
                                                 const unsigned short* __restrict__ gy,
                                                 const float* __restrict__ lsother,
                                                 const int* __restrict__ map,
                                                 float* __restrict__ gxother,
                                                 float* __restrict__ lpost_out,
                                                 const unsigned short* __restrict__ Sread,
                                                 unsigned short* __restrict__ Swrite,
                                                 const unsigned short* __restrict__ Tread,
                                                 unsigned short* __restrict__ Twrite,
                                                 int wmode, int mode, int wrS) {
  const int tid = threadIdx.x;
  const int c = blockIdx.x;                      // one chunk per block
  const int b = tid;                             // wave = b-quarter
  const int kv = c * L_;
  const int kend = kv + L_;

  // ---- issue ALL independent loads upfront ----
  float gvx[L_];
  unsigned short rgy[L_];
#pragma unroll
  for (int i = 0; i < L_; ++i) {
    size_t o = (size_t)(kv + i) * B_ + b;
    gvx[i] = gx[o];
    rgy[i] = gy[o];
  }
  float lsr[L_];
  int jmap[L_];
  if (mode == 0) {
#pragma unroll
    for (int i = 0; i < L_; ++i) jmap[i] = map[kv + i];   // block-uniform
#pragma unroll
    for (int i = 0; i < L_; ++i)
      lsr[i] = lsother[(size_t)jmap[i] * B_ + b];
  }
  uint4 sraw, traw;
  if (wmode == 2) {
    if (c > 0)
      sraw = *(const uint4*)&Sread[((size_t)c * B_ + b) * 8];
    if (c < C_ - 1)
      traw = *(const uint4*)&Tread[((size_t)(c + 1) * B_ + b) * 8];
  }

  // ---- convert valid gamma (gvx kept: needed for extrinsic) ----
  float gc[L_][4];
#pragma unroll
  for (int i = 0; i < L_; ++i) gam_lin(gvx[i], b2f(rgy[i]), gc[i]);

  // ---------------- forward ----------------
  float a[8];
  if (c == 0) {
    a[0] = 1.0f;
#pragma unroll
    for (int s = 1; s < 8; ++s) a[s] = 0.0f;
  } else if (wmode == 0) {
    int wu = kv < W0_ ? kv : W0_;
    if (kv <= W0_) {                 // warmup reaches position 0: exact init
      a[0] = 1.0f;
#pragma unroll
      for (int s = 1; s < 8; ++s) a[s] = 0.0f;
    } else {
#pragma unroll
      for (int s = 0; s < 8; ++s) a[s] = 1.0f;
    }
    int n = wu, k = kv - wu;
    float cx0, cx1;
    unsigned short cy0, cy1;
    if (n > 0) {
      size_t o0 = (size_t)k * B_ + b, o1 = (size_t)(k + 1) * B_ + b;
      cx0 = gx[o0]; cy0 = gy[o0]; cx1 = gx[o1]; cy1 = gy[o1];
    }
    while (n > 0) {
      float nx0, nx1;
      unsigned short ny0, ny1;
      if (n > 2) {
        size_t o0 = (size_t)(k + 2) * B_ + b, o1 = (size_t)(k + 3) * B_ + b;
        nx0 = gx[o0]; ny0 = gy[o0]; nx1 = gx[o1]; ny1 = gy[o1];
      }
      float g[4];
      gam_lin(cx0, b2f(cy0), g); step_fwd_lin(a, g);
      gam_lin(cx1, b2f(cy1), g); step_fwd_lin(a, g);
      renorm_lin(a);
      if (n > 2) { cx0 = nx0; cy0 = ny0; cx1 = nx1; cy1 = ny1; }
      k += 2; n -= 2;
    }
  } else {
    unpack8_bf16(sraw, a);           // pure inheritance (c>0 here)
  }
  // valid region: record alpha, then step (all L steps -> a = alpha(kend))
  float a2d[L_][8];
#pragma unroll
  for (int i = 0; i < L_; ++i) {
#pragma unroll
    for (int s = 0; s < 8; ++s) a2d[i][s] = a[s];
    step_fwd_lin(a, gc[i]);
    if (i & 1) renorm_lin(a);
  }
  if (wrS)
    store8_bf16(&Swrite[((size_t)(c + 1) * B_ + b) * 8], a);

  // ---------------- backward + posterior ----------------
  float bt[8];
  if (c == C_ - 1) {
#pragma unroll
    for (int s = 0; s < 8; ++s) bt[s] = 1.0f;    // exact tail init (uniform)
  } else if (wmode == 0) {
    int rem = K_ - kend;
    int wub = rem < W0_ ? rem : W0_;
#pragma unroll
    for (int s = 0; s < 8; ++s) bt[s] = 1.0f;
    int n = wub, k = kend + wub - 1;
    float cx0, cx1;
    unsigned short cy0, cy1;
    if (n > 0) {
      size_t o0 = (size_t)k * B_ + b, o1 = (size_t)(k - 1) * B_ + b;
      cx0 = gx[o0]; cy0 = gy[o0]; cx1 = gx[o1]; cy1 = gy[o1];
    }
    while (n > 0) {
      float nx0, nx1;
      unsigned short ny0, ny1;
      if (n > 2) {
        size_t o0 = (size_t)(k - 2) * B_ + b, o1 = (size_t)(k - 3) * B_ + b;
        nx0 = gx[o0]; ny0 = gy[o0]; nx1 = gx[o1]; ny1 = gy[o1];
      }
      float g[4];
      gam_lin(cx0, b2f(cy0), g); step_bwd_lin(bt, g);
      gam_lin(cx1, b2f(cy1), g); step_bwd_lin(bt, g);
      renorm_lin(bt);
      if (n > 2) { cx0 = nx0; cy0 = ny0; cx1 = nx1; cy1 = ny1; }
      k -= 2; n -= 2;
    }
  } else {
    unpack8_bf16(traw, bt);          // pure inheritance (c<C_-1 here)
  }
  // valid region, descending: posterior + extrinsic + beta step
#pragma unroll
  for (int ii = 0; ii < L_; ++ii) {
    const int i = L_ - 1 - ii;
    const int kk = kv + i;
    const float* g = gc[i];
    float s00 = 0.0f, s01 = 0.0f, s10 = 0.0f, s11 = 0.0f;
    float bn[8];
#pragma unroll
    for (int s = 0; s < 8; ++s) {
      const int s0 = s & 1, s1b = (s >> 1) & 1, s2b = (s >> 2) & 1;
      const int f0 = s1b ^ s0, q = s1b ^ s2b;
      float b0 = bt[(f0 << 2) | (s >> 1)];
      float b1 = bt[((f0 ^ 1) << 2) | (s >> 1)];
      float m0 = a2d[i][s] * b0;
      float m1 = a2d[i][s] * b1;
      if (q == 0) { s00 += m0; s10 += m1; } else { s01 += m0; s11 += m1; }
      bn[s] = g[q] * b0 + g[2 + (q ^ 1)] * b1;
    }
    float t0 = g[0] * s00 + g[1] * s01;
    float t1 = g[3] * s10 + g[2] * s11;
    float lpost = LOG2F(fmaxf(t0, 1e-37f)) - LOG2F(fmaxf(t1, 1e-37f));
    if (mode == 0) {
      float le = lpost - gvx[i];               // lpost - (ls + la)
      const size_t oo = (size_t)jmap[i] * B_ + b;
      gxother[oo] = lsr[i] + le;
    } else {
      lpost_out[(size_t)kk * B_ + b] = lpost;
    }
#pragma unroll
    for (int s = 0; s < 8; ++s) bt[s] = bn[s];
    if (ii & 1) renorm_lin(bt);
  }
  if (wrS)
    store8_bf16(&Twrite[((size_t)c * B_ + b) * 8], bt);
}

// ---------------- prep: de-interleave + transpose + scale to log2 domain --
__global__ __launch_bounds__(256) void k_prep1(const float* __restrict__ inp,
                                               float* __restrict__ ls1,
                                               float* __restrict__ gx1,
                                               unsigned short* __restrict__ gy1,
                                               unsigned short* __restrict__ gy2) {
  __shared__ float t[3][64][65];
  const int tid = threadIdx.x;
  const int k0 = blockIdx.x * 64, b0 = blockIdx.y * 64;
  const int tk = tid & 63, tq = tid >> 6;
  for (int bb = tq; bb < 64; bb += 4) {
    size_t base = (size_t)(b0 + bb) * (3 * K_) + 3 * (size_t)(k0 + tk);
    t[0][bb][tk] = inp[base + 0];
    t[1][bb][tk] = inp[base + 1];
    t[2][bb][tk] = inp[base + 2];
  }
  __syncthreads();
  const int tb = tid & 63, kq = tid >> 6;
  for (int kk = kq; kk < 64; kk += 4) {
    size_t o = (size_t)(k0 + kk) * B_ + (b0 + tb);
    float sv = -LOG2E * t[0][tb][kk];
    float p1 = -LOG2E * t[1][tb][kk];
    float p2 = -LOG2E * t[2][tb][kk];
    ls1[o] = sv;
    gx1[o] = sv;          // la=0 initially -> lsu = ls
    gy1[o] = f2b(p1);
    gy2[o] = f2b(p2);
  }
}

__global__ __launch_bounds__(256) void k_prep2(const float* __restrict__ ls1,
                                               const int* __restrict__ perm,
                                               float* __restrict__ ls2,
                                               int* __restrict__ inv) {
  const int j = blockIdx.x;
  const int b = threadIdx.x;
  const int p = perm[j];
  ls2[(size_t)j * B_ + b] = ls1[(size_t)p * B_ + b];
  if (b == 0) inv[p] = j;
}

// ---------------- output: out[b,i] = -ln2 * lpost2'[inv[i], b] ------------
__global__ __launch_bounds__(256) void k_out(const float* __restrict__ lpost2t,
                                             const int* __restrict__ inv,
                                             float* __restrict__ out) {
  __shared__ float t[64][65];
  const int tid = threadIdx.x;
  const int i0 = blockIdx.x * 64, b0 = blockIdx.y * 64;
  const int tb = tid & 63, iq = tid >> 6;
  for (int ii = iq; ii < 64; ii += 4) {
    int row = inv[i0 + ii];
    t[ii][tb] = lpost2t[(size_t)row * B_ + (b0 + tb)];
  }
  __syncthreads();
  const int ik = tid & 63, bq = tid >> 6;
  for (int bb = bq; bb < 64; bb += 4) {
    out[(size_t)(b0 + bb) * K_ + (i0 + ik)] = -LN2 * t[ik][bb];
  }
}

// ---------------- launch ---------------------------------------------------
extern "C" void kernel_launch(void* const* d_in, const int* in_sizes, int n_in,
                              void* d_out, int out_size, void* d_ws, size_t ws_size,
                              hipStream_t stream) {
  (void)in_sizes; (void)n_in; (void)out_size; (void)ws_size;
  const float* inp = (const float*)d_in[0];
  const int* perm = (const int*)d_in[1];
  float* out = (float*)d_out;

  char* ws = (char*)d_ws;
  const size_t KB = (size_t)K_ * B_;     // elements per [K][B] plane
  const size_t PB = KB * 4;              // bytes per f32 plane
  const size_t PH = KB * 2;              // bytes per bf16 plane
  float*  gx1     = (float*)(ws);
  float*  gx2     = (float*)(ws + PB);
  float*  ls1     = (float*)(ws + PB * 2);
  float*  ls2     = (float*)(ws + PB * 3);
  float*  lpost2t = (float*)(ws + PB * 4);
  unsigned short* gy1 = (unsigned short*)(ws + PB * 5);
  unsigned short* gy2 = (unsigned short*)(ws + PB * 5 + PH);
  int*    inv     = (int*)(ws + PB * 5 + PH * 2);      // K ints
  // NII boundary-state buffers: [C_+1][B][8] bf16, ping-pong per decoder/dir
  const size_t SB = (size_t)(C_ + 1) * B_ * 8 * 2;     // ~3.15 MB each
  char* nb = ws + PB * 5 + PH * 2 + 65536;
  unsigned short* S1[2] = {(unsigned short*)(nb),          (unsigned short*)(nb + SB)};
  unsigned short* T1[2] = {(unsigned short*)(nb + SB * 2), (unsigned short*)(nb + SB * 3)};
  unsigned short* S2[2] = {(unsigned short*)(nb + SB * 4), (unsigned short*)(nb + SB * 5)};
  unsigned short* T2[2] = {(unsigned short*)(nb + SB * 6), (unsigned short*)(nb + SB * 7)};
  // total: 5*6.3 + 2*3.15 + 8*3.15 MB ~= 63 MB (L3-resident)

  k_prep1<<<dim3(K_ / 64, B_ / 64), 256, 0, stream>>>(inp, ls1, gx1, gy1, gy2);
  k_prep2<<<K_, 256, 0, stream>>>(ls1, perm, ls2, inv);

  for (int it = 0; it < NITER; ++it) {
    const int pr = it & 1, pw = pr ^ 1;   // read prev-iter buffer, write other
    const int wm = (it == 0) ? 0 : 2;
    const int wrS = (it != NITER - 1) ? 1 : 0;
    k_half<<<C_, 256, 0, stream>>>(gx1, gy1, ls2, inv, gx2, lpost2t,
                                   S1[pr], S1[pw], T1[pr], T1[pw],
                                   wm, 0, wrS);
    k_half<<<C_, 256, 0, stream>>>(gx2, gy2, ls1, perm, gx1, lpost2t,
                                   S2[pr], S2[pw], T2[pr], T2[pw],
                                   wm, (it == NITER - 1) ? 1 : 0, wrS);
  }
  k_out<<<dim3(K_ / 64, B_ / 64), 256, 0, stream>>>(lpost2t, inv, out);
}

// Round 13
// 266.678 us; speedup vs baseline: 1.0189x; 1.0189x over previous
//
#include <hip/hip_runtime.h>

// ---------------- problem constants ----------------
constexpr int B_ = 256;        // batch
constexpr int K_ = 6144;       // block length
constexpr int NITER = 6;
constexpr int L_ = 4;          // window valid length -> C_=1536 = 6 blocks/CU
constexpr int W0_ = 32;        // uniform-init warmup (iteration 0)
constexpr int C_ = K_ / L_;    // chunks = 1536
constexpr float LOG2E = 1.4426950408889634f;
constexpr float LN2   = 0.6931471805599453f;

static_assert(K_ % L_ == 0, "");
static_assert((L_ % 2) == 0 && (W0_ % 2) == 0, "");

#if __has_builtin(__builtin_amdgcn_exp2f)
#define EXP2F(x) __builtin_amdgcn_exp2f(x)
#else
#define EXP2F(x) exp2f(x)
#endif
#if __has_builtin(__builtin_amdgcn_logf)
#define LOG2F(x) __builtin_amdgcn_logf(x)
#else
#define LOG2F(x) log2f(x)
#endif
#if __has_builtin(__builtin_amdgcn_rcpf)
#define RCPF(x) __builtin_amdgcn_rcpf(x)
#else
#define RCPF(x) (1.0f / (x))
#endif

// ---- bf16 scalar helpers (RNE) ----
__device__ __forceinline__ float b2f(unsigned short u) {
  return __uint_as_float((unsigned)u << 16);
}
__device__ __forceinline__ unsigned short f2b(float f) {
  unsigned u = __float_as_uint(f);
  u += 0x7FFFu + ((u >> 16) & 1u);
  return (unsigned short)(u >> 16);
}

// trellis: fb(s,u)=u^s1^s0, nxt(s,u)=(fb<<2)|(s>>1), par(s,u)=u^s1^s2
// Linear-domain with normalized gammas: ghat[u][p] = A_u*B_p, A={1,es} by
// sign of gx (es=2^-|gx|), B likewise (ep=2^-|gy|). Common scale cancels in
// the posterior ratio and renormalized alpha/beta -> equivalent to log-MAP.

__device__ __forceinline__ void gam_lin(float gxv, float gyv, float g[4]) {
  float es = EXP2F(-fabsf(gxv));
  float ep = EXP2F(-fabsf(gyv));
  float fu0 = gxv >= 0.0f ? 1.0f : es;
  float fu1 = gxv >= 0.0f ? es : 1.0f;
  float fp0 = gyv >= 0.0f ? 1.0f : ep;
  float fp1 = gyv >= 0.0f ? ep : 1.0f;
  g[0] = fu0 * fp0; g[1] = fu0 * fp1;
  g[2] = fu1 * fp0; g[3] = fu1 * fp1;
}

__device__ __forceinline__ void step_fwd_lin(float a[8], const float g[4]) {
  float an[8];
#pragma unroll
  for (int sn = 0; sn < 8; ++sn) {
    const int u0 = ((sn >> 2) ^ (sn & 1)) & 1;
    const int p0 = ((sn >> 2) ^ ((sn >> 1) & 1)) & 1;
    an[sn] = a[(sn & 3) * 2] * g[u0 * 2 + p0]
           + a[(sn & 3) * 2 + 1] * g[(u0 ^ 1) * 2 + (p0 ^ 1)];
  }
#pragma unroll
  for (int s = 0; s < 8; ++s) a[s] = an[s];
}

__device__ __forceinline__ void step_bwd_lin(float bt[8], const float g[4]) {
  float bn[8];
#pragma unroll
  for (int s = 0; s < 8; ++s) {
    const int s0 = s & 1, s1b = (s >> 1) & 1, s2b = (s >> 2) & 1;
    const int f0 = s1b ^ s0, q = s1b ^ s2b;
    bn[s] = g[q] * bt[(f0 << 2) | (s >> 1)]
          + g[2 + (q ^ 1)] * bt[((f0 ^ 1) << 2) | (s >> 1)];
  }
#pragma unroll
  for (int s = 0; s < 8; ++s) bt[s] = bn[s];
}

// max-renorm with tiny floor injection: NaN/underflow-proof
__device__ __forceinline__ void renorm_lin(float a[8]) {
  float m = fmaxf(fmaxf(fmaxf(a[0], a[1]), fmaxf(a[2], a[3])),
                  fmaxf(fmaxf(a[4], a[5]), fmaxf(a[6], a[7])));
  float r = RCPF(fmaxf(m, 1e-30f));
#pragma unroll
  for (int s = 0; s < 8; ++s) a[s] = fmaf(a[s], r, 1e-32f);
}

// ---- log8-packed boundary states: u8 = round(-16*log2(x)), clamp 255.
// States are renormalized probs in (1e-32, 1]; values below 2^-15.9 clamp
// up to 2^-15.9 (dead components, contribute <=2e-5 to lpost). Max rel
// error 2.2% (half-step of 1/16 log2). 8 bytes per state (was 16 bf16). ----
__device__ __forceinline__ void store8_log8(unsigned char* p, const float a[8]) {
  unsigned int us[8];
#pragma unroll
  for (int s = 0; s < 8; ++s) {
    float l = -16.0f * LOG2F(a[s]);
    l = fminf(l, 255.0f);
    us[s] = (unsigned int)(l + 0.5f);
  }
  uint2 v;
  v.x = us[0] | (us[1] << 8) | (us[2] << 16) | (us[3] << 24);
  v.y = us[4] | (us[5] << 8) | (us[6] << 16) | (us[7] << 24);
  *(uint2*)p = v;
}

__device__ __forceinline__ void unpack8_log8(uint2 v, float a[8]) {
#pragma unroll
  for (int s = 0; s < 4; ++s)
    a[s] = EXP2F(-0.0625f * (float)((v.x >> (8 * s)) & 0xFFu));
#pragma unroll
  for (int s = 0; s < 4; ++s)
    a[4 + s] = EXP2F(-0.0625f * (float)((v.y >> (8 * s)) & 0xFFu));
}

// ---------------- k_half: one windowed BCJR half-iteration (linear) -------
// 256-thread blocks = 4 waves = the 4 b-quarters of ONE chunk.
// gy planes bf16; boundary states log8. wmode 0: uniform warmup W0 (it 0);
// wmode 2: pure inheritance (it>=1). S[c] = alpha at c*L_; T[c] = beta.
// mode 0: scatter extrinsic into other decoder's gx.  mode 1: write lpost.
// wrS 0: skip dead boundary-state stores (last iteration).
__global__ __launch_bounds__(256, 6) void k_half(const float* __restrict__ gx,
                                                 const unsigned short* __restrict__ gy,
                                                 const float* __restrict__ lsother,
                                                 const int* __restrict__ map,
                                                 float* __restrict__ gxother,
                                                 float* __restrict__ lpost_out,
                                                 const unsigned char* __restrict__ Sread,
                                                 unsigned char* __restrict__ Swrite,
                                                 const unsigned char* __restrict__ Tread,
                                                 unsigned char* __restrict__ Twrite,
                                                 int wmode, int mode, int wrS) {
  const int tid = threadIdx.x;
  const int c = blockIdx.x;                      // one chunk per block
  const int b = tid;                             // wave = b-quarter
  const int kv = c * L_;
  const int kend = kv + L_;

  // ---- issue ALL independent loads upfront ----
  float gvx[L_];
  unsigned short rgy[L_];
#pragma unroll
  for (int i = 0; i < L_; ++i) {
    size_t o = (size_t)(kv + i) * B_ + b;
    gvx[i] = gx[o];
    rgy[i] = gy[o];
  }
  float lsr[L_];
  int jmap[L_];
  if (mode == 0) {
#pragma unroll
    for (int i = 0; i < L_; ++i) jmap[i] = map[kv + i];   // block-uniform
#pragma unroll
    for (int i = 0; i < L_; ++i)
      lsr[i] = lsother[(size_t)jmap[i] * B_ + b];
  }
  uint2 sraw, traw;
  if (wmode == 2) {
    if (c > 0)
      sraw = *(const uint2*)&Sread[((size_t)c * B_ + b) * 8];
    if (c < C_ - 1)
      traw = *(const uint2*)&Tread[((size_t)(c + 1) * B_ + b) * 8];
  }

  // ---- convert valid gamma (gvx kept: needed for extrinsic) ----
  float gc[L_][4];
#pragma unroll
  for (int i = 0; i < L_; ++i) gam_lin(gvx[i], b2f(rgy[i]), gc[i]);

  // ---------------- forward ----------------
  float a[8];
  if (c == 0) {
    a[0] = 1.0f;
#pragma unroll
    for (int s = 1; s < 8; ++s) a[s] = 0.0f;
  } else if (wmode == 0) {
    int wu = kv < W0_ ? kv : W0_;
    if (kv <= W0_) {                 // warmup reaches position 0: exact init
      a[0] = 1.0f;
#pragma unroll
      for (int s = 1; s < 8; ++s) a[s] = 0.0f;
    } else {
#pragma unroll
      for (int s = 0; s < 8; ++s) a[s] = 1.0f;
    }
    int n = wu, k = kv - wu;
    float cx0, cx1;
    unsigned short cy0, cy1;
    if (n > 0) {
      size_t o0 = (size_t)k * B_ + b, o1 = (size_t)(k + 1) * B_ + b;
      cx0 = gx[o0]; cy0 = gy[o0]; cx1 = gx[o1]; cy1 = gy[o1];
    }
    while (n > 0) {
      float nx0, nx1;
      unsigned short ny0, ny1;
      if (n > 2) {
        size_t o0 = (size_t)(k + 2) * B_ + b, o1 = (size_t)(k + 3) * B_ + b;
        nx0 = gx[o0]; ny0 = gy[o0]; nx1 = gx[o1]; ny1 = gy[o1];
      }
      float g[4];
      gam_lin(cx0, b2f(cy0), g); step_fwd_lin(a, g);
      gam_lin(cx1, b2f(cy1), g); step_fwd_lin(a, g);
      renorm_lin(a);
      if (n > 2) { cx0 = nx0; cy0 = ny0; cx1 = nx1; cy1 = ny1; }
      k += 2; n -= 2;
    }
  } else {
    unpack8_log8(sraw, a);           // pure inheritance (c>0 here)
  }
  // valid region: record alpha, then step (all L steps -> a = alpha(kend))
  float a2d[L_][8];
#pragma unroll
  for (int i = 0; i < L_; ++i) {
#pragma unroll
    for (int s = 0; s < 8; ++s) a2d[i][s] = a[s];
    step_fwd_lin(a, gc[i]);
    if (i & 1) renorm_lin(a);
  }
  if (wrS)
    store8_log8(&Swrite[((size_t)(c + 1) * B_ + b) * 8], a);

  // ---------------- backward + posterior ----------------
  float bt[8];
  if (c == C_ - 1) {
#pragma unroll
    for (int s = 0; s < 8; ++s) bt[s] = 1.0f;    // exact tail init (uniform)
  } else if (wmode == 0) {
    int rem = K_ - kend;
    int wub = rem < W0_ ? rem : W0_;
#pragma unroll
    for (int s = 0; s < 8; ++s) bt[s] = 1.0f;
    int n = wub, k = kend + wub - 1;
    float cx0, cx1;
    unsigned short cy0, cy1;
    if (n > 0) {
      size_t o0 = (size_t)k * B_ + b, o1 = (size_t)(k - 1) * B_ + b;
      cx0 = gx[o0]; cy0 = gy[o0]; cx1 = gx[o1]; cy1 = gy[o1];
    }
    while (n > 0) {
      float nx0, nx1;
      unsigned short ny0, ny1;
      if (n > 2) {
        size_t o0 = (size_t)(k - 2) * B_ + b, o1 = (size_t)(k - 3) * B_ + b;
        nx0 = gx[o0]; ny0 = gy[o0]; nx1 = gx[o1]; ny1 = gy[o1];
      }
      float g[4];
      gam_lin(cx0, b2f(cy0), g); step_bwd_lin(bt, g);
      gam_lin(cx1, b2f(cy1), g); step_bwd_lin(bt, g);
      renorm_lin(bt);
      if (n > 2) { cx0 = nx0; cy0 = ny0; cx1 = nx1; cy1 = ny1; }
      k -= 2; n -= 2;
    }
  } else {
    unpack8_log8(traw, bt);          // pure inheritance (c<C_-1 here)
  }
  // valid region, descending: posterior + extrinsic + beta step
#pragma unroll
  for (int ii = 0; ii < L_; ++ii) {
    const int i = L_ - 1 - ii;
    const int kk = kv + i;
    const float* g = gc[i];
    float s00 = 0.0f, s01 = 0.0f, s10 = 0.0f, s11 = 0.0f;
    float bn[8];
#pragma unroll
    for (int s = 0; s < 8; ++s) {
      const int s0 = s & 1, s1b = (s >> 1) & 1, s2b = (s >> 2) & 1;
      const int f0 = s1b ^ s0, q = s1b ^ s2b;
      float b0 = bt[(f0 << 2) | (s >> 1)];
      float b1 = bt[((f0 ^ 1) << 2) | (s >> 1)];
      float m0 = a2d[i][s] * b0;
      float m1 = a2d[i][s] * b1;
      if (q == 0) { s00 += m0; s10 += m1; } else { s01 += m0; s11 += m1; }
      bn[s] = g[q] * b0 + g[2 + (q ^ 1)] * b1;
    }
    float t0 = g[0] * s00 + g[1] * s01;
    float t1 = g[3] * s10 + g[2] * s11;
    float lpost = LOG2F(fmaxf(t0, 1e-37f)) - LOG2F(fmaxf(t1, 1e-37f));
    if (mode == 0) {
      float le = lpost - gvx[i];               // lpost - (ls + la)
      const size_t oo = (size_t)jmap[i] * B_ + b;
      gxother[oo] = lsr[i] + le;
    } else {
      lpost_out[(size_t)kk * B_ + b] = lpost;
    }
#pragma unroll
    for (int s = 0; s < 8; ++s) bt[s] = bn[s];
    if (ii & 1) renorm_lin(bt);
  }
  if (wrS)
    store8_log8(&Twrite[((size_t)c * B_ + b) * 8], bt);
}

// ---------------- prep: de-interleave + transpose + scale to log2 domain --
__global__ __launch_bounds__(256) void k_prep1(const float* __restrict__ inp,
                                               float* __restrict__ ls1,
                                               float* __restrict__ gx1,
                                               unsigned short* __restrict__ gy1,
                                               unsigned short* __restrict__ gy2) {
  __shared__ float t[3][64][65];
  const int tid = threadIdx.x;
  const int k0 = blockIdx.x * 64, b0 = blockIdx.y * 64;
  const int tk = tid & 63, tq = tid >> 6;
  for (int bb = tq; bb < 64; bb += 4) {
    size_t base = (size_t)(b0 + bb) * (3 * K_) + 3 * (size_t)(k0 + tk);
    t[0][bb][tk] = inp[base + 0];
    t[1][bb][tk] = inp[base + 1];
    t[2][bb][tk] = inp[base + 2];
  }
  __syncthreads();
  const int tb = tid & 63, kq = tid >> 6;
  for (int kk = kq; kk < 64; kk += 4) {
    size_t o = (size_t)(k0 + kk) * B_ + (b0 + tb);
    float sv = -LOG2E * t[0][tb][kk];
    float p1 = -LOG2E * t[1][tb][kk];
    float p2 = -LOG2E * t[2][tb][kk];
    ls1[o] = sv;
    gx1[o] = sv;          // la=0 initially -> lsu = ls
    gy1[o] = f2b(p1);
    gy2[o] = f2b(p2);
  }
}

__global__ __launch_bounds__(256) void k_prep2(const float* __restrict__ ls1,
                                               const int* __restrict__ perm,
                                               float* __restrict__ ls2,
                                               int* __restrict__ inv) {
  const int j = blockIdx.x;
  const int b = threadIdx.x;
  const int p = perm[j];
  ls2[(size_t)j * B_ + b] = ls1[(size_t)p * B_ + b];
  if (b == 0) inv[p] = j;
}

// ---------------- output: out[b,i] = -ln2 * lpost2'[inv[i], b] ------------
__global__ __launch_bounds__(256) void k_out(const float* __restrict__ lpost2t,
                                             const int* __restrict__ inv,
                                             float* __restrict__ out) {
  __shared__ float t[64][65];
  const int tid = threadIdx.x;
  const int i0 = blockIdx.x * 64, b0 = blockIdx.y * 64;
  const int tb = tid & 63, iq = tid >> 6;
  for (int ii = iq; ii < 64; ii += 4) {
    int row = inv[i0 + ii];
    t[ii][tb] = lpost2t[(size_t)row * B_ + (b0 + tb)];
  }
  __syncthreads();
  const int ik = tid & 63, bq = tid >> 6;
  for (int bb = bq; bb < 64; bb += 4) {
    out[(size_t)(b0 + bb) * K_ + (i0 + ik)] = -LN2 * t[ik][bb];
  }
}

// ---------------- launch ---------------------------------------------------
extern "C" void kernel_launch(void* const* d_in, const int* in_sizes, int n_in,
                              void* d_out, int out_size, void* d_ws, size_t ws_size,
                              hipStream_t stream) {
  (void)in_sizes; (void)n_in; (void)out_size; (void)ws_size;
  const float* inp = (const float*)d_in[0];
  const int* perm = (const int*)d_in[1];
  float* out = (float*)d_out;

  char* ws = (char*)d_ws;
  const size_t KB = (size_t)K_ * B_;     // elements per [K][B] plane
  const size_t PB = KB * 4;              // bytes per f32 plane
  const size_t PH = KB * 2;              // bytes per bf16 plane
  float*  gx1     = (float*)(ws);
  float*  gx2     = (float*)(ws + PB);
  float*  ls1     = (float*)(ws + PB * 2);
  float*  ls2     = (float*)(ws + PB * 3);
  float*  lpost2t = (float*)(ws + PB * 4);
  unsigned short* gy1 = (unsigned short*)(ws + PB * 5);
  unsigned short* gy2 = (unsigned short*)(ws + PB * 5 + PH);
  int*    inv     = (int*)(ws + PB * 5 + PH * 2);      // K ints
  // NII boundary-state buffers: [C_+1][B][8] u8 (log8), ping-pong
  const size_t SB = (size_t)(C_ + 1) * B_ * 8;         // ~3.15 MB each
  char* nb = ws + PB * 5 + PH * 2 + 65536;
  unsigned char* S1[2] = {(unsigned char*)(nb),          (unsigned char*)(nb + SB)};
  unsigned char* T1[2] = {(unsigned char*)(nb + SB * 2), (unsigned char*)(nb + SB * 3)};
  unsigned char* S2[2] = {(unsigned char*)(nb + SB * 4), (unsigned char*)(nb + SB * 5)};
  unsigned char* T2[2] = {(unsigned char*)(nb + SB * 6), (unsigned char*)(nb + SB * 7)};
  // total: 5*6.3 + 2*3.15 + 8*3.15 MB ~= 63 MB (L3-resident)

  k_prep1<<<dim3(K_ / 64, B_ / 64), 256, 0, stream>>>(inp, ls1, gx1, gy1, gy2);
  k_prep2<<<K_, 256, 0, stream>>>(ls1, perm, ls2, inv);

  for (int it = 0; it < NITER; ++it) {
    const int pr = it & 1, pw = pr ^ 1;   // read prev-iter buffer, write other
    const int wm = (it == 0) ? 0 : 2;
    const int wrS = (it != NITER - 1) ? 1 : 0;
    k_half<<<C_, 256, 0, stream>>>(gx1, gy1, ls2, inv, gx2, lpost2t,
                                   S1[pr], S1[pw], T1[pr], T1[pw],
                                   wm, 0, wrS);
    k_half<<<C_, 256, 0, stream>>>(gx2, gy2, ls1, perm, gx1, lpost2t,
                                   S2[pr], S2[pw], T2[pr], T2[pw],
                                   wm, (it == NITER - 1) ? 1 : 0, wrS);
  }
  k_out<<<dim3(K_ / 64, B_ / 64), 256, 0, stream>>>(lpost2t, inv, out);
}

// Round 14
// 246.009 us; speedup vs baseline: 1.1045x; 1.0840x over previous
//
#include <hip/hip_runtime.h>
#include <hip/hip_fp16.h>

// ---------------- problem constants ----------------
constexpr int B_ = 256;        // batch
constexpr int K_ = 6144;       // block length
constexpr int NITER = 6;
constexpr int L_ = 6;          // window valid length -> C_=1024 = 4 blocks/CU
constexpr int W0_ = 32;        // uniform-init warmup (iteration 0)
constexpr int C_ = K_ / L_;    // chunks = 1024
constexpr float LOG2E = 1.4426950408889634f;
constexpr float LN2   = 0.6931471805599453f;

static_assert(K_ % L_ == 0, "");
static_assert((L_ % 2) == 0 && (W0_ % 2) == 0, "");

#if __has_builtin(__builtin_amdgcn_exp2f)
#define EXP2F(x) __builtin_amdgcn_exp2f(x)
#else
#define EXP2F(x) exp2f(x)
#endif
#if __has_builtin(__builtin_amdgcn_logf)
#define LOG2F(x) __builtin_amdgcn_logf(x)
#else
#define LOG2F(x) log2f(x)
#endif
#if __has_builtin(__builtin_amdgcn_rcpf)
#define RCPF(x) __builtin_amdgcn_rcpf(x)
#else
#define RCPF(x) (1.0f / (x))
#endif

// ---- bf16 scalar helpers (RNE) ----
__device__ __forceinline__ float b2f(unsigned short u) {
  return __uint_as_float((unsigned)u << 16);
}
__device__ __forceinline__ unsigned short f2b(float f) {
  unsigned u = __float_as_uint(f);
  u += 0x7FFFu + ((u >> 16) & 1u);
  return (unsigned short)(u >> 16);
}

// trellis: fb(s,u)=u^s1^s0, nxt(s,u)=(fb<<2)|(s>>1), par(s,u)=u^s1^s2
// Linear-domain with normalized gammas: ghat[u][p] = A_u*B_p, A={1,es} by
// sign of gx (es=2^-|gx|), B likewise (ep=2^-|gy|). Common scale cancels in
// the posterior ratio and renormalized alpha/beta -> equivalent to log-MAP.

__device__ __forceinline__ void gam_lin(float gxv, float gyv, float g[4]) {
  float es = EXP2F(-fabsf(gxv));
  float ep = EXP2F(-fabsf(gyv));
  float fu0 = gxv >= 0.0f ? 1.0f : es;
  float fu1 = gxv >= 0.0f ? es : 1.0f;
  float fp0 = gyv >= 0.0f ? 1.0f : ep;
  float fp1 = gyv >= 0.0f ? ep : 1.0f;
  g[0] = fu0 * fp0; g[1] = fu0 * fp1;
  g[2] = fu1 * fp0; g[3] = fu1 * fp1;
}

__device__ __forceinline__ void step_fwd_lin(float a[8], const float g[4]) {
  float an[8];
#pragma unroll
  for (int sn = 0; sn < 8; ++sn) {
    const int u0 = ((sn >> 2) ^ (sn & 1)) & 1;
    const int p0 = ((sn >> 2) ^ ((sn >> 1) & 1)) & 1;
    an[sn] = a[(sn & 3) * 2] * g[u0 * 2 + p0]
           + a[(sn & 3) * 2 + 1] * g[(u0 ^ 1) * 2 + (p0 ^ 1)];
  }
#pragma unroll
  for (int s = 0; s < 8; ++s) a[s] = an[s];
}

__device__ __forceinline__ void step_bwd_lin(float bt[8], const float g[4]) {
  float bn[8];
#pragma unroll
  for (int s = 0; s < 8; ++s) {
    const int s0 = s & 1, s1b = (s >> 1) & 1, s2b = (s >> 2) & 1;
    const int f0 = s1b ^ s0, q = s1b ^ s2b;
    bn[s] = g[q] * bt[(f0 << 2) | (s >> 1)]
          + g[2 + (q ^ 1)] * bt[((f0 ^ 1) << 2) | (s >> 1)];
  }
#pragma unroll
  for (int s = 0; s < 8; ++s) bt[s] = bn[s];
}

// max-renorm with tiny floor injection: NaN/underflow-proof
__device__ __forceinline__ void renorm_lin(float a[8]) {
  float m = fmaxf(fmaxf(fmaxf(a[0], a[1]), fmaxf(a[2], a[3])),
                  fmaxf(fmaxf(a[4], a[5]), fmaxf(a[6], a[7])));
  float r = RCPF(fmaxf(m, 1e-30f));
#pragma unroll
  for (int s = 0; s < 8; ++s) a[s] = fmaf(a[s], r, 1e-32f);
}

// ---- log8-packed boundary states: u8 = round(-16*log2(x)), clamp 255.
// States are renormalized probs in (1e-32, 1]; values below 2^-15.9 clamp
// up (dead components, contribute <=2e-5 to lpost). Max rel error 2.2%. ----
__device__ __forceinline__ void store8_log8(unsigned char* p, const float a[8]) {
  unsigned int us[8];
#pragma unroll
  for (int s = 0; s < 8; ++s) {
    float l = -16.0f * LOG2F(a[s]);
    l = fminf(l, 255.0f);
    us[s] = (unsigned int)(l + 0.5f);
  }
  uint2 v;
  v.x = us[0] | (us[1] << 8) | (us[2] << 16) | (us[3] << 24);
  v.y = us[4] | (us[5] << 8) | (us[6] << 16) | (us[7] << 24);
  *(uint2*)p = v;
}

__device__ __forceinline__ void unpack8_log8(uint2 v, float a[8]) {
#pragma unroll
  for (int s = 0; s < 4; ++s)
    a[s] = EXP2F(-0.0625f * (float)((v.x >> (8 * s)) & 0xFFu));
#pragma unroll
  for (int s = 0; s < 4; ++s)
    a[4 + s] = EXP2F(-0.0625f * (float)((v.y >> (8 * s)) & 0xFFu));
}

// ---------------- k_half: one windowed BCJR half-iteration (linear) -------
// 256-thread blocks = 4 waves = the 4 b-quarters of ONE chunk.
// gy planes bf16; ls planes fp16 (static, |ls|<~8 -> 0.05% rel err);
// boundary states log8; gx (iterated extrinsic) stays f32.
// wmode 0: uniform warmup W0 (it 0); wmode 2: pure inheritance (it>=1).
// mode 0: scatter extrinsic into other decoder's gx.  mode 1: write lpost.
// wrS 0: skip dead boundary-state stores (last iteration).
__global__ __launch_bounds__(256, 4) void k_half(const float* __restrict__ gx,
                                                 const unsigned short* __restrict__ gy,
                                                 const __half* __restrict__ lsother,
                                                 const int* __restrict__ map,
                                                 float* __restrict__ gxother,
                                                 float* __restrict__ lpost_out,
                                                 const unsigned char* __restrict__ Sread,
                                                 unsigned char* __restrict__ Swrite,
                                                 const unsigned char* __restrict__ Tread,
                                                 unsigned char* __restrict__ Twrite,
                                                 int wmode, int mode, int wrS) {
  const int tid = threadIdx.x;
  const int c = blockIdx.x;                      // one chunk per block
  const int b = tid;                             // wave = b-quarter
  const int kv = c * L_;
  const int kend = kv + L_;

  // ---- issue ALL independent loads upfront ----
  float gvx[L_];
  unsigned short rgy[L_];
#pragma unroll
  for (int i = 0; i < L_; ++i) {
    size_t o = (size_t)(kv + i) * B_ + b;
    gvx[i] = gx[o];
    rgy[i] = gy[o];
  }
  float lsr[L_];
  int jmap[L_];
  if (mode == 0) {
#pragma unroll
    for (int i = 0; i < L_; ++i) jmap[i] = map[kv + i];   // block-uniform
#pragma unroll
    for (int i = 0; i < L_; ++i)
      lsr[i] = __half2float(lsother[(size_t)jmap[i] * B_ + b]);
  }
  uint2 sraw, traw;
  if (wmode == 2) {
    if (c > 0)
      sraw = *(const uint2*)&Sread[((size_t)c * B_ + b) * 8];
    if (c < C_ - 1)
      traw = *(const uint2*)&Tread[((size_t)(c + 1) * B_ + b) * 8];
  }

  // ---- convert valid gamma (gvx kept: needed for extrinsic) ----
  float gc[L_][4];
#pragma unroll
  for (int i = 0; i < L_; ++i) gam_lin(gvx[i], b2f(rgy[i]), gc[i]);

  // ---------------- forward ----------------
  float a[8];
  if (c == 0) {
    a[0] = 1.0f;
#pragma unroll
    for (int s = 1; s < 8; ++s) a[s] = 0.0f;
  } else if (wmode == 0) {
    int wu = kv < W0_ ? kv : W0_;
    if (kv <= W0_) {                 // warmup reaches position 0: exact init
      a[0] = 1.0f;
#pragma unroll
      for (int s = 1; s < 8; ++s) a[s] = 0.0f;
    } else {
#pragma unroll
      for (int s = 0; s < 8; ++s) a[s] = 1.0f;
    }
    int n = wu, k = kv - wu;
    float cx0, cx1;
    unsigned short cy0, cy1;
    if (n > 0) {
      size_t o0 = (size_t)k * B_ + b, o1 = (size_t)(k + 1) * B_ + b;
      cx0 = gx[o0]; cy0 = gy[o0]; cx1 = gx[o1]; cy1 = gy[o1];
    }
    while (n > 0) {
      float nx0, nx1;
      unsigned short ny0, ny1;
      if (n > 2) {
        size_t o0 = (size_t)(k + 2) * B_ + b, o1 = (size_t)(k + 3) * B_ + b;
        nx0 = gx[o0]; ny0 = gy[o0]; nx1 = gx[o1]; ny1 = gy[o1];
      }
      float g[4];
      gam_lin(cx0, b2f(cy0), g); step_fwd_lin(a, g);
      gam_lin(cx1, b2f(cy1), g); step_fwd_lin(a, g);
      renorm_lin(a);
      if (n > 2) { cx0 = nx0; cy0 = ny0; cx1 = nx1; cy1 = ny1; }
      k += 2; n -= 2;
    }
  } else {
    unpack8_log8(sraw, a);           // pure inheritance (c>0 here)
  }
  // valid region: record alpha, then step (all L steps -> a = alpha(kend))
  float a2d[L_][8];
#pragma unroll
  for (int i = 0; i < L_; ++i) {
#pragma unroll
    for (int s = 0; s < 8; ++s) a2d[i][s] = a[s];
    step_fwd_lin(a, gc[i]);
    if (i & 1) renorm_lin(a);
  }
  if (wrS)
    store8_log8(&Swrite[((size_t)(c + 1) * B_ + b) * 8], a);

  // ---------------- backward + posterior ----------------
  float bt[8];
  if (c == C_ - 1) {
#pragma unroll
    for (int s = 0; s < 8; ++s) bt[s] = 1.0f;    // exact tail init (uniform)
  } else if (wmode == 0) {
    int rem = K_ - kend;
    int wub = rem < W0_ ? rem : W0_;
#pragma unroll
    for (int s = 0; s < 8; ++s) bt[s] = 1.0f;
    int n = wub, k = kend + wub - 1;
    float cx0, cx1;
    unsigned short cy0, cy1;
    if (n > 0) {
      size_t o0 = (size_t)k * B_ + b, o1 = (size_t)(k - 1) * B_ + b;
      cx0 = gx[o0]; cy0 = gy[o0]; cx1 = gx[o1]; cy1 = gy[o1];
    }
    while (n > 0) {
      float nx0, nx1;
      unsigned short ny0, ny1;
      if (n > 2) {
        size_t o0 = (size_t)(k - 2) * B_ + b, o1 = (size_t)(k - 3) * B_ + b;
        nx0 = gx[o0]; ny0 = gy[o0]; nx1 = gx[o1]; ny1 = gy[o1];
      }
      float g[4];
      gam_lin(cx0, b2f(cy0), g); step_bwd_lin(bt, g);
      gam_lin(cx1, b2f(cy1), g); step_bwd_lin(bt, g);
      renorm_lin(bt);
      if (n > 2) { cx0 = nx0; cy0 = ny0; cx1 = nx1; cy1 = ny1; }
      k -= 2; n -= 2;
    }
  } else {
    unpack8_log8(traw, bt);          // pure inheritance (c<C_-1 here)
  }
  // valid region, descending: posterior + extrinsic + beta step
#pragma unroll
  for (int ii = 0; ii < L_; ++ii) {
    const int i = L_ - 1 - ii;
    const int kk = kv + i;
    const float* g = gc[i];
    float s00 = 0.0f, s01 = 0.0f, s10 = 0.0f, s11 = 0.0f;
    float bn[8];
#pragma unroll
    for (int s = 0; s < 8; ++s) {
      const int s0 = s & 1, s1b = (s >> 1) & 1, s2b = (s >> 2) & 1;
      const int f0 = s1b ^ s0, q = s1b ^ s2b;
      float b0 = bt[(f0 << 2) | (s >> 1)];
      float b1 = bt[((f0 ^ 1) << 2) | (s >> 1)];
      float m0 = a2d[i][s] * b0;
      float m1 = a2d[i][s] * b1;
      if (q == 0) { s00 += m0; s10 += m1; } else { s01 += m0; s11 += m1; }
      bn[s] = g[q] * b0 + g[2 + (q ^ 1)] * b1;
    }
    float t0 = g[0] * s00 + g[1] * s01;
    float t1 = g[3] * s10 + g[2] * s11;
    float lpost = LOG2F(fmaxf(t0, 1e-37f)) - LOG2F(fmaxf(t1, 1e-37f));
    if (mode == 0) {
      float le = lpost - gvx[i];               // lpost - (ls + la)
      const size_t oo = (size_t)jmap[i] * B_ + b;
      gxother[oo] = lsr[i] + le;
    } else {
      lpost_out[(size_t)kk * B_ + b] = lpost;
    }
#pragma unroll
    for (int s = 0; s < 8; ++s) bt[s] = bn[s];
    if (ii & 1) renorm_lin(bt);
  }
  if (wrS)
    store8_log8(&Twrite[((size_t)c * B_ + b) * 8], bt);
}

// ---------------- prep: de-interleave + transpose + scale to log2 domain --
__global__ __launch_bounds__(256) void k_prep1(const float* __restrict__ inp,
                                               __half* __restrict__ ls1,
                                               float* __restrict__ gx1,
                                               unsigned short* __restrict__ gy1,
                                               unsigned short* __restrict__ gy2) {
  __shared__ float t[3][64][65];
  const int tid = threadIdx.x;
  const int k0 = blockIdx.x * 64, b0 = blockIdx.y * 64;
  const int tk = tid & 63, tq = tid >> 6;
  for (int bb = tq; bb < 64; bb += 4) {
    size_t base = (size_t)(b0 + bb) * (3 * K_) + 3 * (size_t)(k0 + tk);
    t[0][bb][tk] = inp[base + 0];
    t[1][bb][tk] = inp[base + 1];
    t[2][bb][tk] = inp[base + 2];
  }
  __syncthreads();
  const int tb = tid & 63, kq = tid >> 6;
  for (int kk = kq; kk < 64; kk += 4) {
    size_t o = (size_t)(k0 + kk) * B_ + (b0 + tb);
    float sv = -LOG2E * t[0][tb][kk];
    float p1 = -LOG2E * t[1][tb][kk];
    float p2 = -LOG2E * t[2][tb][kk];
    ls1[o] = __float2half(sv);
    gx1[o] = sv;          // la=0 initially -> lsu = ls
    gy1[o] = f2b(p1);
    gy2[o] = f2b(p2);
  }
}

// 4 rows per block to amortize launch width
__global__ __launch_bounds__(256) void k_prep2(const __half* __restrict__ ls1,
                                               const int* __restrict__ perm,
                                               __half* __restrict__ ls2,
                                               int* __restrict__ inv) {
  const int b = threadIdx.x;
#pragma unroll
  for (int r = 0; r < 4; ++r) {
    const int j = blockIdx.x * 4 + r;
    const int p = perm[j];
    ls2[(size_t)j * B_ + b] = ls1[(size_t)p * B_ + b];
    if (b == 0) inv[p] = j;
  }
}

// ---------------- output: out[b,i] = -ln2 * lpost2'[inv[i], b] ------------
__global__ __launch_bounds__(256) void k_out(const float* __restrict__ lpost2t,
                                             const int* __restrict__ inv,
                                             float* __restrict__ out) {
  __shared__ float t[64][65];
  const int tid = threadIdx.x;
  const int i0 = blockIdx.x * 64, b0 = blockIdx.y * 64;
  const int tb = tid & 63, iq = tid >> 6;
  for (int ii = iq; ii < 64; ii += 4) {
    int row = inv[i0 + ii];
    t[ii][tb] = lpost2t[(size_t)row * B_ + (b0 + tb)];
  }
  __syncthreads();
  const int ik = tid & 63, bq = tid >> 6;
  for (int bb = bq; bb < 64; bb += 4) {
    out[(size_t)(b0 + bb) * K_ + (i0 + ik)] = -LN2 * t[ik][bb];
  }
}

// ---------------- launch ---------------------------------------------------
extern "C" void kernel_launch(void* const* d_in, const int* in_sizes, int n_in,
                              void* d_out, int out_size, void* d_ws, size_t ws_size,
                              hipStream_t stream) {
  (void)in_sizes; (void)n_in; (void)out_size; (void)ws_size;
  const float* inp = (const float*)d_in[0];
  const int* perm = (const int*)d_in[1];
  float* out = (float*)d_out;

  char* ws = (char*)d_ws;
  const size_t KB = (size_t)K_ * B_;     // elements per [K][B] plane
  const size_t PB = KB * 4;              // bytes per f32 plane
  const size_t PH = KB * 2;              // bytes per 16-bit plane
  float*  gx1     = (float*)(ws);
  float*  gx2     = (float*)(ws + PB);
  float*  lpost2t = (float*)(ws + PB * 2);
  unsigned short* gy1 = (unsigned short*)(ws + PB * 3);
  unsigned short* gy2 = (unsigned short*)(ws + PB * 3 + PH);
  __half* ls1     = (__half*)(ws + PB * 3 + PH * 2);
  __half* ls2     = (__half*)(ws + PB * 3 + PH * 3);
  int*    inv     = (int*)(ws + PB * 3 + PH * 4);      // K ints
  // NII boundary-state buffers: [C_+1][B][8] u8 (log8), ping-pong
  const size_t SB = (size_t)(C_ + 1) * B_ * 8;         // ~2.1 MB each
  char* nb = ws + PB * 3 + PH * 4 + 65536;
  unsigned char* S1[2] = {(unsigned char*)(nb),          (unsigned char*)(nb + SB)};
  unsigned char* T1[2] = {(unsigned char*)(nb + SB * 2), (unsigned char*)(nb + SB * 3)};
  unsigned char* S2[2] = {(unsigned char*)(nb + SB * 4), (unsigned char*)(nb + SB * 5)};
  unsigned char* T2[2] = {(unsigned char*)(nb + SB * 6), (unsigned char*)(nb + SB * 7)};
  // total: 3*6.3 + 4*3.15 + 8*2.1 MB ~= 48 MB (L3-resident)

  k_prep1<<<dim3(K_ / 64, B_ / 64), 256, 0, stream>>>(inp, ls1, gx1, gy1, gy2);
  k_prep2<<<K_ / 4, 256, 0, stream>>>(ls1, perm, ls2, inv);

  for (int it = 0; it < NITER; ++it) {
    const int pr = it & 1, pw = pr ^ 1;   // read prev-iter buffer, write other
    const int wm = (it == 0) ? 0 : 2;
    const int wrS = (it != NITER - 1) ? 1 : 0;
    k_half<<<C_, 256, 0, stream>>>(gx1, gy1, ls2, inv, gx2, lpost2t,
                                   S1[pr], S1[pw], T1[pr], T1[pw],
                                   wm, 0, wrS);
    k_half<<<C_, 256, 0, stream>>>(gx2, gy2, ls1, perm, gx1, lpost2t,
                                   S2[pr], S2[pw], T2[pr], T2[pw],
                                   wm, (it == NITER - 1) ? 1 : 0, wrS);
  }
  k_out<<<dim3(K_ / 64, B_ / 64), 256, 0, stream>>>(lpost2t, inv, out);
}

// Round 15
// 243.447 us; speedup vs baseline: 1.1161x; 1.0105x over previous
//
#include <hip/hip_runtime.h>
#include <hip/hip_fp16.h>

// ---------------- problem constants ----------------
constexpr int B_ = 256;        // batch
constexpr int K_ = 6144;       // block length
constexpr int NITER = 6;
constexpr int L_ = 6;          // window valid length -> C_=1024 = 4 blocks/CU
constexpr int W0_ = 32;        // uniform-init warmup (iteration 0)
constexpr int C_ = K_ / L_;    // chunks = 1024
constexpr float LOG2E = 1.4426950408889634f;
constexpr float LN2   = 0.6931471805599453f;

static_assert(K_ % L_ == 0, "");
static_assert((L_ % 2) == 0 && (W0_ % 2) == 0, "");

#if __has_builtin(__builtin_amdgcn_exp2f)
#define EXP2F(x) __builtin_amdgcn_exp2f(x)
#else
#define EXP2F(x) exp2f(x)
#endif
#if __has_builtin(__builtin_amdgcn_logf)
#define LOG2F(x) __builtin_amdgcn_logf(x)
#else
#define LOG2F(x) log2f(x)
#endif
#if __has_builtin(__builtin_amdgcn_rcpf)
#define RCPF(x) __builtin_amdgcn_rcpf(x)
#else
#define RCPF(x) (1.0f / (x))
#endif

// ---- bf16 scalar helpers (RNE) ----
__device__ __forceinline__ float b2f(unsigned short u) {
  return __uint_as_float((unsigned)u << 16);
}
__device__ __forceinline__ unsigned short f2b(float f) {
  unsigned u = __float_as_uint(f);
  u += 0x7FFFu + ((u >> 16) & 1u);
  return (unsigned short)(u >> 16);
}

// trellis: fb(s,u)=u^s1^s0, nxt(s,u)=(fb<<2)|(s>>1), par(s,u)=u^s1^s2
// Linear-domain with normalized gammas: ghat[u][p] = A_u*B_p, A={1,es} by
// sign of gx (es=2^-|gx|), B likewise (ep=2^-|gy|). Common scale cancels in
// the posterior ratio and renormalized alpha/beta -> equivalent to log-MAP.

__device__ __forceinline__ void gam_lin(float gxv, float gyv, float g[4]) {
  float es = EXP2F(-fabsf(gxv));
  float ep = EXP2F(-fabsf(gyv));
  float fu0 = gxv >= 0.0f ? 1.0f : es;
  float fu1 = gxv >= 0.0f ? es : 1.0f;
  float fp0 = gyv >= 0.0f ? 1.0f : ep;
  float fp1 = gyv >= 0.0f ? ep : 1.0f;
  g[0] = fu0 * fp0; g[1] = fu0 * fp1;
  g[2] = fu1 * fp0; g[3] = fu1 * fp1;
}

__device__ __forceinline__ void step_fwd_lin(float a[8], const float g[4]) {
  float an[8];
#pragma unroll
  for (int sn = 0; sn < 8; ++sn) {
    const int u0 = ((sn >> 2) ^ (sn & 1)) & 1;
    const int p0 = ((sn >> 2) ^ ((sn >> 1) & 1)) & 1;
    an[sn] = a[(sn & 3) * 2] * g[u0 * 2 + p0]
           + a[(sn & 3) * 2 + 1] * g[(u0 ^ 1) * 2 + (p0 ^ 1)];
  }
#pragma unroll
  for (int s = 0; s < 8; ++s) a[s] = an[s];
}

__device__ __forceinline__ void step_bwd_lin(float bt[8], const float g[4]) {
  float bn[8];
#pragma unroll
  for (int s = 0; s < 8; ++s) {
    const int s0 = s & 1, s1b = (s >> 1) & 1, s2b = (s >> 2) & 1;
    const int f0 = s1b ^ s0, q = s1b ^ s2b;
    bn[s] = g[q] * bt[(f0 << 2) | (s >> 1)]
          + g[2 + (q ^ 1)] * bt[((f0 ^ 1) << 2) | (s >> 1)];
  }
#pragma unroll
  for (int s = 0; s < 8; ++s) bt[s] = bn[s];
}

// max-renorm with tiny floor injection: NaN/underflow-proof
__device__ __forceinline__ void renorm_lin(float a[8]) {
  float m = fmaxf(fmaxf(fmaxf(a[0], a[1]), fmaxf(a[2], a[3])),
                  fmaxf(fmaxf(a[4], a[5]), fmaxf(a[6], a[7])));
  float r = RCPF(fmaxf(m, 1e-30f));
#pragma unroll
  for (int s = 0; s < 8; ++s) a[s] = fmaf(a[s], r, 1e-32f);
}

// ---- log8-packed boundary states: u8 = round(-16*log2(x)), clamp 255.
// States are renormalized probs in (1e-32, 1]; values below 2^-15.9 clamp
// up (dead components, contribute <=2e-5 to lpost). Max rel error 2.2%. ----
__device__ __forceinline__ void store8_log8(unsigned char* p, const float a[8]) {
  unsigned int us[8];
#pragma unroll
  for (int s = 0; s < 8; ++s) {
    float l = -16.0f * LOG2F(a[s]);
    l = fminf(l, 255.0f);
    us[s] = (unsigned int)(l + 0.5f);
  }
  uint2 v;
  v.x = us[0] | (us[1] << 8) | (us[2] << 16) | (us[3] << 24);
  v.y = us[4] | (us[5] << 8) | (us[6] << 16) | (us[7] << 24);
  *(uint2*)p = v;
}

__device__ __forceinline__ void unpack8_log8(uint2 v, float a[8]) {
#pragma unroll
  for (int s = 0; s < 4; ++s)
    a[s] = EXP2F(-0.0625f * (float)((v.x >> (8 * s)) & 0xFFu));
#pragma unroll
  for (int s = 0; s < 4; ++s)
    a[4 + s] = EXP2F(-0.0625f * (float)((v.y >> (8 * s)) & 0xFFu));
}

// ---------------- k_half: one windowed BCJR half-iteration (linear) -------
// 256-thread blocks = 4 waves = the 4 b-quarters of ONE chunk.
// gx planes fp16 (|lsu|<~50 -> 0.05% rel err; same rounded value feeds both
// gamma and the extrinsic subtraction, keeping the update self-consistent);
// gy planes bf16; ls planes fp16; boundary states log8.
// wmode 0: uniform warmup W0 (it 0); wmode 2: pure inheritance (it>=1).
// mode 0: scatter extrinsic into other decoder's gx.  mode 1: write lpost.
// wrS 0: skip dead boundary-state stores (last iteration).
__global__ __launch_bounds__(256, 4) void k_half(const __half* __restrict__ gx,
                                                 const unsigned short* __restrict__ gy,
                                                 const __half* __restrict__ lsother,
                                                 const int* __restrict__ map,
                                                 __half* __restrict__ gxother,
                                                 float* __restrict__ lpost_out,
                                                 const unsigned char* __restrict__ Sread,
                                                 unsigned char* __restrict__ Swrite,
                                                 const unsigned char* __restrict__ Tread,
                                                 unsigned char* __restrict__ Twrite,
                                                 int wmode, int mode, int wrS) {
  const int tid = threadIdx.x;
  const int c = blockIdx.x;                      // one chunk per block
  const int b = tid;                             // wave = b-quarter
  const int kv = c * L_;
  const int kend = kv + L_;

  // ---- issue ALL independent loads upfront ----
  __half hgx[L_];
  unsigned short rgy[L_];
#pragma unroll
  for (int i = 0; i < L_; ++i) {
    size_t o = (size_t)(kv + i) * B_ + b;
    hgx[i] = gx[o];
    rgy[i] = gy[o];
  }
  float lsr[L_];
  int jmap[L_];
  if (mode == 0) {
#pragma unroll
    for (int i = 0; i < L_; ++i) jmap[i] = map[kv + i];   // block-uniform
#pragma unroll
    for (int i = 0; i < L_; ++i)
      lsr[i] = __half2float(lsother[(size_t)jmap[i] * B_ + b]);
  }
  uint2 sraw, traw;
  if (wmode == 2) {
    if (c > 0)
      sraw = *(const uint2*)&Sread[((size_t)c * B_ + b) * 8];
    if (c < C_ - 1)
      traw = *(const uint2*)&Tread[((size_t)(c + 1) * B_ + b) * 8];
  }

  // ---- convert valid gamma (gvx kept: needed for extrinsic) ----
  float gvx[L_];
  float gc[L_][4];
#pragma unroll
  for (int i = 0; i < L_; ++i) {
    gvx[i] = __half2float(hgx[i]);
    gam_lin(gvx[i], b2f(rgy[i]), gc[i]);
  }

  // ---------------- forward ----------------
  float a[8];
  if (c == 0) {
    a[0] = 1.0f;
#pragma unroll
    for (int s = 1; s < 8; ++s) a[s] = 0.0f;
  } else if (wmode == 0) {
    int wu = kv < W0_ ? kv : W0_;
    if (kv <= W0_) {                 // warmup reaches position 0: exact init
      a[0] = 1.0f;
#pragma unroll
      for (int s = 1; s < 8; ++s) a[s] = 0.0f;
    } else {
#pragma unroll
      for (int s = 0; s < 8; ++s) a[s] = 1.0f;
    }
    int n = wu, k = kv - wu;
    __half cx0, cx1;
    unsigned short cy0, cy1;
    if (n > 0) {
      size_t o0 = (size_t)k * B_ + b, o1 = (size_t)(k + 1) * B_ + b;
      cx0 = gx[o0]; cy0 = gy[o0]; cx1 = gx[o1]; cy1 = gy[o1];
    }
    while (n > 0) {
      __half nx0, nx1;
      unsigned short ny0, ny1;
      if (n > 2) {
        size_t o0 = (size_t)(k + 2) * B_ + b, o1 = (size_t)(k + 3) * B_ + b;
        nx0 = gx[o0]; ny0 = gy[o0]; nx1 = gx[o1]; ny1 = gy[o1];
      }
      float g[4];
      gam_lin(__half2float(cx0), b2f(cy0), g); step_fwd_lin(a, g);
      gam_lin(__half2float(cx1), b2f(cy1), g); step_fwd_lin(a, g);
      renorm_lin(a);
      if (n > 2) { cx0 = nx0; cy0 = ny0; cx1 = nx1; cy1 = ny1; }
      k += 2; n -= 2;
    }
  } else {
    unpack8_log8(sraw, a);           // pure inheritance (c>0 here)
  }
  // valid region: record alpha, then step (all L steps -> a = alpha(kend))
  float a2d[L_][8];
#pragma unroll
  for (int i = 0; i < L_; ++i) {
#pragma unroll
    for (int s = 0; s < 8; ++s) a2d[i][s] = a[s];
    step_fwd_lin(a, gc[i]);
    if (i & 1) renorm_lin(a);
  }
  if (wrS)
    store8_log8(&Swrite[((size_t)(c + 1) * B_ + b) * 8], a);

  // ---------------- backward + posterior ----------------
  float bt[8];
  if (c == C_ - 1) {
#pragma unroll
    for (int s = 0; s < 8; ++s) bt[s] = 1.0f;    // exact tail init (uniform)
  } else if (wmode == 0) {
    int rem = K_ - kend;
    int wub = rem < W0_ ? rem : W0_;
#pragma unroll
    for (int s = 0; s < 8; ++s) bt[s] = 1.0f;
    int n = wub, k = kend + wub - 1;
    __half cx0, cx1;
    unsigned short cy0, cy1;
    if (n > 0) {
      size_t o0 = (size_t)k * B_ + b, o1 = (size_t)(k - 1) * B_ + b;
      cx0 = gx[o0]; cy0 = gy[o0]; cx1 = gx[o1]; cy1 = gy[o1];
    }
    while (n > 0) {
      __half nx0, nx1;
      unsigned short ny0, ny1;
      if (n > 2) {
        size_t o0 = (size_t)(k - 2) * B_ + b, o1 = (size_t)(k - 3) * B_ + b;
        nx0 = gx[o0]; ny0 = gy[o0]; nx1 = gx[o1]; ny1 = gy[o1];
      }
      float g[4];
      gam_lin(__half2float(cx0), b2f(cy0), g); step_bwd_lin(bt, g);
      gam_lin(__half2float(cx1), b2f(cy1), g); step_bwd_lin(bt, g);
      renorm_lin(bt);
      if (n > 2) { cx0 = nx0; cy0 = ny0; cx1 = nx1; cy1 = ny1; }
      k -= 2; n -= 2;
    }
  } else {
    unpack8_log8(traw, bt);          // pure inheritance (c<C_-1 here)
  }
  // valid region, descending: posterior + extrinsic + beta step
#pragma unroll
  for (int ii = 0; ii < L_; ++ii) {
    const int i = L_ - 1 - ii;
    const int kk = kv + i;
    const float* g = gc[i];
    float s00 = 0.0f, s01 = 0.0f, s10 = 0.0f, s11 = 0.0f;
    float bn[8];
#pragma unroll
    for (int s = 0; s < 8; ++s) {
      const int s0 = s & 1, s1b = (s >> 1) & 1, s2b = (s >> 2) & 1;
      const int f0 = s1b ^ s0, q = s1b ^ s2b;
      float b0 = bt[(f0 << 2) | (s >> 1)];
      float b1 = bt[((f0 ^ 1) << 2) | (s >> 1)];
      float m0 = a2d[i][s] * b0;
      float m1 = a2d[i][s] * b1;
      if (q == 0) { s00 += m0; s10 += m1; } else { s01 += m0; s11 += m1; }
      bn[s] = g[q] * b0 + g[2 + (q ^ 1)] * b1;
    }
    float t0 = g[0] * s00 + g[1] * s01;
    float t1 = g[3] * s10 + g[2] * s11;
    float lpost = LOG2F(fmaxf(t0, 1e-37f)) - LOG2F(fmaxf(t1, 1e-37f));
    if (mode == 0) {
      float le = lpost - gvx[i];               // lpost - (ls + la)
      const size_t oo = (size_t)jmap[i] * B_ + b;
      gxother[oo] = __float2half(lsr[i] + le);
    } else {
      lpost_out[(size_t)kk * B_ + b] = lpost;
    }
#pragma unroll
    for (int s = 0; s < 8; ++s) bt[s] = bn[s];
    if (ii & 1) renorm_lin(bt);
  }
  if (wrS)
    store8_log8(&Twrite[((size_t)c * B_ + b) * 8], bt);
}

// ---------------- prep: de-interleave + transpose + scale to log2 domain --
__global__ __launch_bounds__(256) void k_prep1(const float* __restrict__ inp,
                                               __half* __restrict__ ls1,
                                               __half* __restrict__ gx1,
                                               unsigned short* __restrict__ gy1,
                                               unsigned short* __restrict__ gy2) {
  __shared__ float t[3][64][65];
  const int tid = threadIdx.x;
  const int k0 = blockIdx.x * 64, b0 = blockIdx.y * 64;
  const int tk = tid & 63, tq = tid >> 6;
  for (int bb = tq; bb < 64; bb += 4) {
    size_t base = (size_t)(b0 + bb) * (3 * K_) + 3 * (size_t)(k0 + tk);
    t[0][bb][tk] = inp[base + 0];
    t[1][bb][tk] = inp[base + 1];
    t[2][bb][tk] = inp[base + 2];
  }
  __syncthreads();
  const int tb = tid & 63, kq = tid >> 6;
  for (int kk = kq; kk < 64; kk += 4) {
    size_t o = (size_t)(k0 + kk) * B_ + (b0 + tb);
    float sv = -LOG2E * t[0][tb][kk];
    float p1 = -LOG2E * t[1][tb][kk];
    float p2 = -LOG2E * t[2][tb][kk];
    ls1[o] = __float2half(sv);
    gx1[o] = __float2half(sv);   // la=0 initially -> lsu = ls
    gy1[o] = f2b(p1);
    gy2[o] = f2b(p2);
  }
}

// 4 rows per block to amortize launch width
__global__ __launch_bounds__(256) void k_prep2(const __half* __restrict__ ls1,
                                               const int* __restrict__ perm,
                                               __half* __restrict__ ls2,
                                               int* __restrict__ inv) {
  const int b = threadIdx.x;
#pragma unroll
  for (int r = 0; r < 4; ++r) {
    const int j = blockIdx.x * 4 + r;
    const int p = perm[j];
    ls2[(size_t)j * B_ + b] = ls1[(size_t)p * B_ + b];
    if (b == 0) inv[p] = j;
  }
}

// ---------------- output: out[b,i] = -ln2 * lpost2'[inv[i], b] ------------
__global__ __launch_bounds__(256) void k_out(const float* __restrict__ lpost2t,
                                             const int* __restrict__ inv,
                                             float* __restrict__ out) {
  __shared__ float t[64][65];
  const int tid = threadIdx.x;
  const int i0 = blockIdx.x * 64, b0 = blockIdx.y * 64;
  const int tb = tid & 63, iq = tid >> 6;
  for (int ii = iq; ii < 64; ii += 4) {
    int row = inv[i0 + ii];
    t[ii][tb] = lpost2t[(size_t)row * B_ + (b0 + tb)];
  }
  __syncthreads();
  const int ik = tid & 63, bq = tid >> 6;
  for (int bb = bq; bb < 64; bb += 4) {
    out[(size_t)(b0 + bb) * K_ + (i0 + ik)] = -LN2 * t[ik][bb];
  }
}

// ---------------- launch ---------------------------------------------------
extern "C" void kernel_launch(void* const* d_in, const int* in_sizes, int n_in,
                              void* d_out, int out_size, void* d_ws, size_t ws_size,
                              hipStream_t stream) {
  (void)in_sizes; (void)n_in; (void)out_size; (void)ws_size;
  const float* inp = (const float*)d_in[0];
  const int* perm = (const int*)d_in[1];
  float* out = (float*)d_out;

  char* ws = (char*)d_ws;
  const size_t KB = (size_t)K_ * B_;     // elements per [K][B] plane
  const size_t PB = KB * 4;              // bytes per f32 plane
  const size_t PH = KB * 2;              // bytes per 16-bit plane
  float*  lpost2t = (float*)(ws);
  __half* gx1     = (__half*)(ws + PB);
  __half* gx2     = (__half*)(ws + PB + PH);
  unsigned short* gy1 = (unsigned short*)(ws + PB + PH * 2);
  unsigned short* gy2 = (unsigned short*)(ws + PB + PH * 3);
  __half* ls1     = (__half*)(ws + PB + PH * 4);
  __half* ls2     = (__half*)(ws + PB + PH * 5);
  int*    inv     = (int*)(ws + PB + PH * 6);          // K ints
  // NII boundary-state buffers: [C_+1][B][8] u8 (log8), ping-pong
  const size_t SB = (size_t)(C_ + 1) * B_ * 8;         // ~2.1 MB each
  char* nb = ws + PB + PH * 6 + 65536;
  unsigned char* S1[2] = {(unsigned char*)(nb),          (unsigned char*)(nb + SB)};
  unsigned char* T1[2] = {(unsigned char*)(nb + SB * 2), (unsigned char*)(nb + SB * 3)};
  unsigned char* S2[2] = {(unsigned char*)(nb + SB * 4), (unsigned char*)(nb + SB * 5)};
  unsigned char* T2[2] = {(unsigned char*)(nb + SB * 6), (unsigned char*)(nb + SB * 7)};
  // total: 6.3 + 6*3.15 + 8*2.1 MB ~= 42 MB (L3-resident)

  k_prep1<<<dim3(K_ / 64, B_ / 64), 256, 0, stream>>>(inp, ls1, gx1, gy1, gy2);
  k_prep2<<<K_ / 4, 256, 0, stream>>>(ls1, perm, ls2, inv);

  for (int it = 0; it < NITER; ++it) {
    const int pr = it & 1, pw = pr ^ 1;   // read prev-iter buffer, write other
    const int wm = (it == 0) ? 0 : 2;
    const int wrS = (it != NITER - 1) ? 1 : 0;
    k_half<<<C_, 256, 0, stream>>>(gx1, gy1, ls2, inv, gx2, lpost2t,
                                   S1[pr], S1[pw], T1[pr], T1[pw],
                                   wm, 0, wrS);
    k_half<<<C_, 256, 0, stream>>>(gx2, gy2, ls1, perm, gx1, lpost2t,
                                   S2[pr], S2[pw], T2[pr], T2[pw],
                                   wm, (it == NITER - 1) ? 1 : 0, wrS);
  }
  k_out<<<dim3(K_ / 64, B_ / 64), 256, 0, stream>>>(lpost2t, inv, out);
}

// Round 16
// 237.391 us; speedup vs baseline: 1.1446x; 1.0255x over previous
//
#include <hip/hip_runtime.h>
#include <hip/hip_fp16.h>

// ---------------- problem constants ----------------
constexpr int B_ = 256;        // batch
constexpr int K_ = 6144;       // block length
constexpr int NITER = 6;
constexpr int L_ = 6;          // window valid length -> C_=1024 = 4 blocks/CU
constexpr int W0_ = 32;        // uniform-init warmup (iteration 0)
constexpr int C_ = K_ / L_;    // chunks = 1024
constexpr float LOG2E = 1.4426950408889634f;
constexpr float LN2   = 0.6931471805599453f;

static_assert(K_ % L_ == 0, "");
static_assert((L_ % 2) == 0 && (W0_ % 2) == 0, "");

#if __has_builtin(__builtin_amdgcn_exp2f)
#define EXP2F(x) __builtin_amdgcn_exp2f(x)
#else
#define EXP2F(x) exp2f(x)
#endif
#if __has_builtin(__builtin_amdgcn_logf)
#define LOG2F(x) __builtin_amdgcn_logf(x)
#else
#define LOG2F(x) log2f(x)
#endif
#if __has_builtin(__builtin_amdgcn_rcpf)
#define RCPF(x) __builtin_amdgcn_rcpf(x)
#else
#define RCPF(x) (1.0f / (x))
#endif

// ---- bf16 scalar helpers (RNE) ----
__device__ __forceinline__ float b2f(unsigned short u) {
  return __uint_as_float((unsigned)u << 16);
}
__device__ __forceinline__ unsigned short f2b(float f) {
  unsigned u = __float_as_uint(f);
  u += 0x7FFFu + ((u >> 16) & 1u);
  return (unsigned short)(u >> 16);
}

// trellis: fb(s,u)=u^s1^s0, nxt(s,u)=(fb<<2)|(s>>1), par(s,u)=u^s1^s2
// Linear-domain with normalized gammas: ghat[u][p] = A_u*B_p, A={1,es} by
// sign of gx (es=2^-|gx|), B likewise (ep=2^-|gy|). Common scale cancels in
// the posterior ratio and renormalized alpha/beta -> equivalent to log-MAP.

__device__ __forceinline__ void gam_lin(float gxv, float gyv, float g[4]) {
  float es = EXP2F(-fabsf(gxv));
  float ep = EXP2F(-fabsf(gyv));
  float fu0 = gxv >= 0.0f ? 1.0f : es;
  float fu1 = gxv >= 0.0f ? es : 1.0f;
  float fp0 = gyv >= 0.0f ? 1.0f : ep;
  float fp1 = gyv >= 0.0f ? ep : 1.0f;
  g[0] = fu0 * fp0; g[1] = fu0 * fp1;
  g[2] = fu1 * fp0; g[3] = fu1 * fp1;
}

__device__ __forceinline__ void step_fwd_lin(float a[8], const float g[4]) {
  float an[8];
#pragma unroll
  for (int sn = 0; sn < 8; ++sn) {
    const int u0 = ((sn >> 2) ^ (sn & 1)) & 1;
    const int p0 = ((sn >> 2) ^ ((sn >> 1) & 1)) & 1;
    an[sn] = a[(sn & 3) * 2] * g[u0 * 2 + p0]
           + a[(sn & 3) * 2 + 1] * g[(u0 ^ 1) * 2 + (p0 ^ 1)];
  }
#pragma unroll
  for (int s = 0; s < 8; ++s) a[s] = an[s];
}

__device__ __forceinline__ void step_bwd_lin(float bt[8], const float g[4]) {
  float bn[8];
#pragma unroll
  for (int s = 0; s < 8; ++s) {
    const int s0 = s & 1, s1b = (s >> 1) & 1, s2b = (s >> 2) & 1;
    const int f0 = s1b ^ s0, q = s1b ^ s2b;
    bn[s] = g[q] * bt[(f0 << 2) | (s >> 1)]
          + g[2 + (q ^ 1)] * bt[((f0 ^ 1) << 2) | (s >> 1)];
  }
#pragma unroll
  for (int s = 0; s < 8; ++s) bt[s] = bn[s];
}

// max-renorm with tiny floor injection: NaN/underflow-proof
__device__ __forceinline__ void renorm_lin(float a[8]) {
  float m = fmaxf(fmaxf(fmaxf(a[0], a[1]), fmaxf(a[2], a[3])),
                  fmaxf(fmaxf(a[4], a[5]), fmaxf(a[6], a[7])));
  float r = RCPF(fmaxf(m, 1e-30f));
#pragma unroll
  for (int s = 0; s < 8; ++s) a[s] = fmaf(a[s], r, 1e-32f);
}

// ---- log8-packed boundary states: u8 = round(-16*log2(x)), clamp 255.
// States are renormalized probs in (1e-32, 1]; values below 2^-15.9 clamp
// up (dead components, contribute <=2e-5 to lpost). Max rel error 2.2%. ----
__device__ __forceinline__ void store8_log8(unsigned char* p, const float a[8]) {
  unsigned int us[8];
#pragma unroll
  for (int s = 0; s < 8; ++s) {
    float l = -16.0f * LOG2F(a[s]);
    l = fminf(l, 255.0f);
    us[s] = (unsigned int)(l + 0.5f);
  }
  uint2 v;
  v.x = us[0] | (us[1] << 8) | (us[2] << 16) | (us[3] << 24);
  v.y = us[4] | (us[5] << 8) | (us[6] << 16) | (us[7] << 24);
  *(uint2*)p = v;
}

__device__ __forceinline__ void unpack8_log8(uint2 v, float a[8]) {
#pragma unroll
  for (int s = 0; s < 4; ++s)
    a[s] = EXP2F(-0.0625f * (float)((v.x >> (8 * s)) & 0xFFu));
#pragma unroll
  for (int s = 0; s < 4; ++s)
    a[4 + s] = EXP2F(-0.0625f * (float)((v.y >> (8 * s)) & 0xFFu));
}

// ---------------- k_half: one windowed BCJR half-iteration (linear) -------
// 256-thread blocks = 4 waves = the 4 b-quarters of ONE chunk.
// gx planes fp16; gy planes bf16; ls planes fp16; boundary states log8.
// Permutation identity: lsother[map[kk]] == lsloc[kk] (prep2 copies rows),
// so the extrinsic uses the LOCAL ls plane (coalesced, no random gather).
// wmode 0: uniform warmup W0 (it 0); wmode 2: pure inheritance (it>=1).
// mode 0: scatter extrinsic into other decoder's gx at row map[kk].
// mode 1: write lpost at ORIGINAL-domain row map[kk]=perm[kk] -> k_out
//         becomes a plain transpose (no inv gather).
// wrS 0: skip dead boundary-state stores (last iteration).
__global__ __launch_bounds__(256, 4) void k_half(const __half* __restrict__ gx,
                                                 const unsigned short* __restrict__ gy,
                                                 const __half* __restrict__ lsloc,
                                                 const int* __restrict__ map,
                                                 __half* __restrict__ gxother,
                                                 float* __restrict__ lpost_out,
                                                 const unsigned char* __restrict__ Sread,
                                                 unsigned char* __restrict__ Swrite,
                                                 const unsigned char* __restrict__ Tread,
                                                 unsigned char* __restrict__ Twrite,
                                                 int wmode, int mode, int wrS) {
  const int tid = threadIdx.x;
  const int c = blockIdx.x;                      // one chunk per block
  const int b = tid;                             // wave = b-quarter
  const int kv = c * L_;
  const int kend = kv + L_;

  // ---- issue ALL independent loads upfront ----
  __half hgx[L_];
  unsigned short rgy[L_];
  __half hls[L_];
#pragma unroll
  for (int i = 0; i < L_; ++i) {
    size_t o = (size_t)(kv + i) * B_ + b;
    hgx[i] = gx[o];
    rgy[i] = gy[o];
  }
  if (mode == 0) {
#pragma unroll
    for (int i = 0; i < L_; ++i)
      hls[i] = lsloc[(size_t)(kv + i) * B_ + b];   // local rows, coalesced
  }
  int jmap[L_];
#pragma unroll
  for (int i = 0; i < L_; ++i) jmap[i] = map[kv + i];     // block-uniform
  uint2 sraw, traw;
  if (wmode == 2) {
    if (c > 0)
      sraw = *(const uint2*)&Sread[((size_t)c * B_ + b) * 8];
    if (c < C_ - 1)
      traw = *(const uint2*)&Tread[((size_t)(c + 1) * B_ + b) * 8];
  }

  // ---- convert valid gamma (gvx kept: needed for extrinsic) ----
  float gvx[L_];
  float gc[L_][4];
#pragma unroll
  for (int i = 0; i < L_; ++i) {
    gvx[i] = __half2float(hgx[i]);
    gam_lin(gvx[i], b2f(rgy[i]), gc[i]);
  }

  // ---------------- forward ----------------
  float a[8];
  if (c == 0) {
    a[0] = 1.0f;
#pragma unroll
    for (int s = 1; s < 8; ++s) a[s] = 0.0f;
  } else if (wmode == 0) {
    int wu = kv < W0_ ? kv : W0_;
    if (kv <= W0_) {                 // warmup reaches position 0: exact init
      a[0] = 1.0f;
#pragma unroll
      for (int s = 1; s < 8; ++s) a[s] = 0.0f;
    } else {
#pragma unroll
      for (int s = 0; s < 8; ++s) a[s] = 1.0f;
    }
    int n = wu, k = kv - wu;
    __half cx0, cx1;
    unsigned short cy0, cy1;
    if (n > 0) {
      size_t o0 = (size_t)k * B_ + b, o1 = (size_t)(k + 1) * B_ + b;
      cx0 = gx[o0]; cy0 = gy[o0]; cx1 = gx[o1]; cy1 = gy[o1];
    }
    while (n > 0) {
      __half nx0, nx1;
      unsigned short ny0, ny1;
      if (n > 2) {
        size_t o0 = (size_t)(k + 2) * B_ + b, o1 = (size_t)(k + 3) * B_ + b;
        nx0 = gx[o0]; ny0 = gy[o0]; nx1 = gx[o1]; ny1 = gy[o1];
      }
      float g[4];
      gam_lin(__half2float(cx0), b2f(cy0), g); step_fwd_lin(a, g);
      gam_lin(__half2float(cx1), b2f(cy1), g); step_fwd_lin(a, g);
      renorm_lin(a);
      if (n > 2) { cx0 = nx0; cy0 = ny0; cx1 = nx1; cy1 = ny1; }
      k += 2; n -= 2;
    }
  } else {
    unpack8_log8(sraw, a);           // pure inheritance (c>0 here)
  }
  // valid region: record alpha, then step (all L steps -> a = alpha(kend))
  float a2d[L_][8];
#pragma unroll
  for (int i = 0; i < L_; ++i) {
#pragma unroll
    for (int s = 0; s < 8; ++s) a2d[i][s] = a[s];
    step_fwd_lin(a, gc[i]);
    if (i & 1) renorm_lin(a);
  }
  if (wrS)
    store8_log8(&Swrite[((size_t)(c + 1) * B_ + b) * 8], a);

  // ---------------- backward + posterior ----------------
  float bt[8];
  if (c == C_ - 1) {
#pragma unroll
    for (int s = 0; s < 8; ++s) bt[s] = 1.0f;    // exact tail init (uniform)
  } else if (wmode == 0) {
    int rem = K_ - kend;
    int wub = rem < W0_ ? rem : W0_;
#pragma unroll
    for (int s = 0; s < 8; ++s) bt[s] = 1.0f;
    int n = wub, k = kend + wub - 1;
    __half cx0, cx1;
    unsigned short cy0, cy1;
    if (n > 0) {
      size_t o0 = (size_t)k * B_ + b, o1 = (size_t)(k - 1) * B_ + b;
      cx0 = gx[o0]; cy0 = gy[o0]; cx1 = gx[o1]; cy1 = gy[o1];
    }
    while (n > 0) {
      __half nx0, nx1;
      unsigned short ny0, ny1;
      if (n > 2) {
        size_t o0 = (size_t)(k - 2) * B_ + b, o1 = (size_t)(k - 3) * B_ + b;
        nx0 = gx[o0]; ny0 = gy[o0]; nx1 = gx[o1]; ny1 = gy[o1];
      }
      float g[4];
      gam_lin(__half2float(cx0), b2f(cy0), g); step_bwd_lin(bt, g);
      gam_lin(__half2float(cx1), b2f(cy1), g); step_bwd_lin(bt, g);
      renorm_lin(bt);
      if (n > 2) { cx0 = nx0; cy0 = ny0; cx1 = nx1; cy1 = ny1; }
      k -= 2; n -= 2;
    }
  } else {
    unpack8_log8(traw, bt);          // pure inheritance (c<C_-1 here)
  }
  // valid region, descending: posterior + extrinsic + beta step
#pragma unroll
  for (int ii = 0; ii < L_; ++ii) {
    const int i = L_ - 1 - ii;
    const float* g = gc[i];
    float s00 = 0.0f, s01 = 0.0f, s10 = 0.0f, s11 = 0.0f;
    float bn[8];
#pragma unroll
    for (int s = 0; s < 8; ++s) {
      const int s0 = s & 1, s1b = (s >> 1) & 1, s2b = (s >> 2) & 1;
      const int f0 = s1b ^ s0, q = s1b ^ s2b;
      float b0 = bt[(f0 << 2) | (s >> 1)];
      float b1 = bt[((f0 ^ 1) << 2) | (s >> 1)];
      float m0 = a2d[i][s] * b0;
      float m1 = a2d[i][s] * b1;
      if (q == 0) { s00 += m0; s10 += m1; } else { s01 += m0; s11 += m1; }
      bn[s] = g[q] * b0 + g[2 + (q ^ 1)] * b1;
    }
    float t0 = g[0] * s00 + g[1] * s01;
    float t1 = g[3] * s10 + g[2] * s11;
    float lpost = LOG2F(fmaxf(t0, 1e-37f)) - LOG2F(fmaxf(t1, 1e-37f));
    const size_t oo = (size_t)jmap[i] * B_ + b;
    if (mode == 0) {
      float le = lpost - gvx[i];               // lpost - (ls + la)
      gxother[oo] = __float2half(__half2float(hls[i]) + le);
    } else {
      lpost_out[oo] = lpost;                   // original-domain row perm[kk]
    }
#pragma unroll
    for (int s = 0; s < 8; ++s) bt[s] = bn[s];
    if (ii & 1) renorm_lin(bt);
  }
  if (wrS)
    store8_log8(&Twrite[((size_t)c * B_ + b) * 8], bt);
}

// ---------------- prep: de-interleave + transpose + scale to log2 domain --
__global__ __launch_bounds__(256) void k_prep1(const float* __restrict__ inp,
                                               __half* __restrict__ ls1,
                                               __half* __restrict__ gx1,
                                               unsigned short* __restrict__ gy1,
                                               unsigned short* __restrict__ gy2) {
  __shared__ float t[3][64][65];
  const int tid = threadIdx.x;
  const int k0 = blockIdx.x * 64, b0 = blockIdx.y * 64;
  const int tk = tid & 63, tq = tid >> 6;
  for (int bb = tq; bb < 64; bb += 4) {
    size_t base = (size_t)(b0 + bb) * (3 * K_) + 3 * (size_t)(k0 + tk);
    t[0][bb][tk] = inp[base + 0];
    t[1][bb][tk] = inp[base + 1];
    t[2][bb][tk] = inp[base + 2];
  }
  __syncthreads();
  const int tb = tid & 63, kq = tid >> 6;
  for (int kk = kq; kk < 64; kk += 4) {
    size_t o = (size_t)(k0 + kk) * B_ + (b0 + tb);
    float sv = -LOG2E * t[0][tb][kk];
    float p1 = -LOG2E * t[1][tb][kk];
    float p2 = -LOG2E * t[2][tb][kk];
    ls1[o] = __float2half(sv);
    gx1[o] = __float2half(sv);   // la=0 initially -> lsu = ls
    gy1[o] = f2b(p1);
    gy2[o] = f2b(p2);
  }
}

// 4 rows per block to amortize launch width
__global__ __launch_bounds__(256) void k_prep2(const __half* __restrict__ ls1,
                                               const int* __restrict__ perm,
                                               __half* __restrict__ ls2,
                                               int* __restrict__ inv) {
  const int b = threadIdx.x;
#pragma unroll
  for (int r = 0; r < 4; ++r) {
    const int j = blockIdx.x * 4 + r;
    const int p = perm[j];
    ls2[(size_t)j * B_ + b] = ls1[(size_t)p * B_ + b];
    if (b == 0) inv[p] = j;
  }
}

// ---------------- output: out[b,i] = -ln2 * lpostT[i, b] (plain transpose)
__global__ __launch_bounds__(256) void k_out(const float* __restrict__ lpostT,
                                             float* __restrict__ out) {
  __shared__ float t[64][65];
  const int tid = threadIdx.x;
  const int i0 = blockIdx.x * 64, b0 = blockIdx.y * 64;
  const int tb = tid & 63, iq = tid >> 6;
  for (int ii = iq; ii < 64; ii += 4) {
    t[ii][tb] = lpostT[(size_t)(i0 + ii) * B_ + (b0 + tb)];
  }
  __syncthreads();
  const int ik = tid & 63, bq = tid >> 6;
  for (int bb = bq; bb < 64; bb += 4) {
    out[(size_t)(b0 + bb) * K_ + (i0 + ik)] = -LN2 * t[ik][bb];
  }
}

// ---------------- launch ---------------------------------------------------
extern "C" void kernel_launch(void* const* d_in, const int* in_sizes, int n_in,
                              void* d_out, int out_size, void* d_ws, size_t ws_size,
                              hipStream_t stream) {
  (void)in_sizes; (void)n_in; (void)out_size; (void)ws_size;
  const float* inp = (const float*)d_in[0];
  const int* perm = (const int*)d_in[1];
  float* out = (float*)d_out;

  char* ws = (char*)d_ws;
  const size_t KB = (size_t)K_ * B_;     // elements per [K][B] plane
  const size_t PB = KB * 4;              // bytes per f32 plane
  const size_t PH = KB * 2;              // bytes per 16-bit plane
  float*  lpostT  = (float*)(ws);
  __half* gx1     = (__half*)(ws + PB);
  __half* gx2     = (__half*)(ws + PB + PH);
  unsigned short* gy1 = (unsigned short*)(ws + PB + PH * 2);
  unsigned short* gy2 = (unsigned short*)(ws + PB + PH * 3);
  __half* ls1     = (__half*)(ws + PB + PH * 4);
  __half* ls2     = (__half*)(ws + PB + PH * 5);
  int*    inv     = (int*)(ws + PB + PH * 6);          // K ints
  // NII boundary-state buffers: [C_+1][B][8] u8 (log8), ping-pong
  const size_t SB = (size_t)(C_ + 1) * B_ * 8;         // ~2.1 MB each
  char* nb = ws + PB + PH * 6 + 65536;
  unsigned char* S1[2] = {(unsigned char*)(nb),          (unsigned char*)(nb + SB)};
  unsigned char* T1[2] = {(unsigned char*)(nb + SB * 2), (unsigned char*)(nb + SB * 3)};
  unsigned char* S2[2] = {(unsigned char*)(nb + SB * 4), (unsigned char*)(nb + SB * 5)};
  unsigned char* T2[2] = {(unsigned char*)(nb + SB * 6), (unsigned char*)(nb + SB * 7)};
  // total: 6.3 + 6*3.15 + 8*2.1 MB ~= 42 MB (L3-resident)

  k_prep1<<<dim3(K_ / 64, B_ / 64), 256, 0, stream>>>(inp, ls1, gx1, gy1, gy2);
  k_prep2<<<K_ / 4, 256, 0, stream>>>(ls1, perm, ls2, inv);

  for (int it = 0; it < NITER; ++it) {
    const int pr = it & 1, pw = pr ^ 1;   // read prev-iter buffer, write other
    const int wm = (it == 0) ? 0 : 2;
    const int wrS = (it != NITER - 1) ? 1 : 0;
    // phase 0 (decoder 1): extrinsic -> gx2[inv[kk]]; local ls plane = ls1
    k_half<<<C_, 256, 0, stream>>>(gx1, gy1, ls1, inv, gx2, lpostT,
                                   S1[pr], S1[pw], T1[pr], T1[pw],
                                   wm, 0, wrS);
    // phase 1 (decoder 2): extrinsic -> gx1[perm[kk]]; local ls plane = ls2
    k_half<<<C_, 256, 0, stream>>>(gx2, gy2, ls2, perm, gx1, lpostT,
                                   S2[pr], S2[pw], T2[pr], T2[pw],
                                   wm, (it == NITER - 1) ? 1 : 0, wrS);
  }
  k_out<<<dim3(K_ / 64, B_ / 64), 256, 0, stream>>>(lpostT, out);
}

// Round 17
// 208.938 us; speedup vs baseline: 1.3004x; 1.1362x over previous
//
#include <hip/hip_runtime.h>
#include <hip/hip_fp16.h>

// ---------------- problem constants ----------------
constexpr int B_ = 256;        // batch
constexpr int K_ = 6144;       // block length
constexpr int NITER = 6;
constexpr int L_ = 6;          // window valid length -> C_=1024 = 4 blocks/CU
constexpr int W0_ = 12;        // uniform-init warmup (iteration 0)
constexpr int C_ = K_ / L_;    // chunks = 1024
constexpr float LOG2E = 1.4426950408889634f;
constexpr float LN2   = 0.6931471805599453f;

static_assert(K_ % L_ == 0, "");
static_assert((L_ % 2) == 0 && (W0_ % 2) == 0, "");

#if __has_builtin(__builtin_amdgcn_exp2f)
#define EXP2F(x) __builtin_amdgcn_exp2f(x)
#else
#define EXP2F(x) exp2f(x)
#endif
#if __has_builtin(__builtin_amdgcn_logf)
#define LOG2F(x) __builtin_amdgcn_logf(x)
#else
#define LOG2F(x) log2f(x)
#endif
#if __has_builtin(__builtin_amdgcn_rcpf)
#define RCPF(x) __builtin_amdgcn_rcpf(x)
#else
#define RCPF(x) (1.0f / (x))
#endif

// ---- bf16 scalar helpers (RNE) ----
__device__ __forceinline__ float b2f(unsigned short u) {
  return __uint_as_float((unsigned)u << 16);
}
__device__ __forceinline__ unsigned short f2b(float f) {
  unsigned u = __float_as_uint(f);
  u += 0x7FFFu + ((u >> 16) & 1u);
  return (unsigned short)(u >> 16);
}

// trellis: fb(s,u)=u^s1^s0, nxt(s,u)=(fb<<2)|(s>>1), par(s,u)=u^s1^s2
// Linear-domain with normalized gammas: ghat[u][p] = A_u*B_p, A={1,es} by
// sign of gx (es=2^-|gx|), B likewise (ep=2^-|gy|). Common scale cancels in
// the posterior ratio and renormalized alpha/beta -> equivalent to log-MAP.

__device__ __forceinline__ void gam_lin(float gxv, float gyv, float g[4]) {
  float es = EXP2F(-fabsf(gxv));
  float ep = EXP2F(-fabsf(gyv));
  float fu0 = gxv >= 0.0f ? 1.0f : es;
  float fu1 = gxv >= 0.0f ? es : 1.0f;
  float fp0 = gyv >= 0.0f ? 1.0f : ep;
  float fp1 = gyv >= 0.0f ? ep : 1.0f;
  g[0] = fu0 * fp0; g[1] = fu0 * fp1;
  g[2] = fu1 * fp0; g[3] = fu1 * fp1;
}

__device__ __forceinline__ void step_fwd_lin(float a[8], const float g[4]) {
  float an[8];
#pragma unroll
  for (int sn = 0; sn < 8; ++sn) {
    const int u0 = ((sn >> 2) ^ (sn & 1)) & 1;
    const int p0 = ((sn >> 2) ^ ((sn >> 1) & 1)) & 1;
    an[sn] = a[(sn & 3) * 2] * g[u0 * 2 + p0]
           + a[(sn & 3) * 2 + 1] * g[(u0 ^ 1) * 2 + (p0 ^ 1)];
  }
#pragma unroll
  for (int s = 0; s < 8; ++s) a[s] = an[s];
}

__device__ __forceinline__ void step_bwd_lin(float bt[8], const float g[4]) {
  float bn[8];
#pragma unroll
  for (int s = 0; s < 8; ++s) {
    const int s0 = s & 1, s1b = (s >> 1) & 1, s2b = (s >> 2) & 1;
    const int f0 = s1b ^ s0, q = s1b ^ s2b;
    bn[s] = g[q] * bt[(f0 << 2) | (s >> 1)]
          + g[2 + (q ^ 1)] * bt[((f0 ^ 1) << 2) | (s >> 1)];
  }
#pragma unroll
  for (int s = 0; s < 8; ++s) bt[s] = bn[s];
}

// max-renorm with tiny floor injection: NaN/underflow-proof
__device__ __forceinline__ void renorm_lin(float a[8]) {
  float m = fmaxf(fmaxf(fmaxf(a[0], a[1]), fmaxf(a[2], a[3])),
                  fmaxf(fmaxf(a[4], a[5]), fmaxf(a[6], a[7])));
  float r = RCPF(fmaxf(m, 1e-30f));
#pragma unroll
  for (int s = 0; s < 8; ++s) a[s] = fmaf(a[s], r, 1e-32f);
}

// ---- log8-packed boundary states: u8 = round(-16*log2(x)), clamp 255.
// States are renormalized probs in (1e-32, 1]; values below 2^-15.9 clamp
// up (dead components, contribute <=2e-5 to lpost). Max rel error 2.2%. ----
__device__ __forceinline__ void store8_log8(unsigned char* p, const float a[8]) {
  unsigned int us[8];
#pragma unroll
  for (int s = 0; s < 8; ++s) {
    float l = -16.0f * LOG2F(a[s]);
    l = fminf(l, 255.0f);
    us[s] = (unsigned int)(l + 0.5f);
  }
  uint2 v;
  v.x = us[0] | (us[1] << 8) | (us[2] << 16) | (us[3] << 24);
  v.y = us[4] | (us[5] << 8) | (us[6] << 16) | (us[7] << 24);
  *(uint2*)p = v;
}

__device__ __forceinline__ void unpack8_log8(uint2 v, float a[8]) {
#pragma unroll
  for (int s = 0; s < 4; ++s)
    a[s] = EXP2F(-0.0625f * (float)((v.x >> (8 * s)) & 0xFFu));
#pragma unroll
  for (int s = 0; s < 4; ++s)
    a[4 + s] = EXP2F(-0.0625f * (float)((v.y >> (8 * s)) & 0xFFu));
}

// ---------------- k_half: one windowed BCJR half-iteration (linear) -------
// 256-thread blocks = 4 waves = the 4 b-quarters of ONE chunk.
// gx planes fp16; gy planes bf16; ls planes fp16; boundary states log8.
// Permutation identity: lsother[map[kk]] == lsloc[kk], so the extrinsic
// uses the LOCAL ls plane (coalesced, no random gather). At it0 the caller
// passes lsloc AS gx (bit-identical: la=0).
// wmode 0: uniform warmup W0 (it 0); wmode 2: pure inheritance (it>=1).
// mode 0: scatter extrinsic into other decoder's gx at row map[kk].
// mode 1: write -ln2*lpost at ORIGINAL-domain row map[kk]=perm[kk] ->
//         k_out becomes a plain transpose-copy.
// wrS 0: skip dead boundary-state stores (last iteration).
__global__ __launch_bounds__(256, 4) void k_half(const __half* __restrict__ gx,
                                                 const unsigned short* __restrict__ gy,
                                                 const __half* __restrict__ lsloc,
                                                 const int* __restrict__ map,
                                                 __half* __restrict__ gxother,
                                                 float* __restrict__ lpost_out,
                                                 const unsigned char* __restrict__ Sread,
                                                 unsigned char* __restrict__ Swrite,
                                                 const unsigned char* __restrict__ Tread,
                                                 unsigned char* __restrict__ Twrite,
                                                 int wmode, int mode, int wrS) {
  const int tid = threadIdx.x;
  const int c = blockIdx.x;                      // one chunk per block
  const int b = tid;                             // wave = b-quarter
  const int kv = c * L_;
  const int kend = kv + L_;

  // ---- issue ALL independent loads upfront ----
  __half hgx[L_];
  unsigned short rgy[L_];
  __half hls[L_];
#pragma unroll
  for (int i = 0; i < L_; ++i) {
    size_t o = (size_t)(kv + i) * B_ + b;
    hgx[i] = gx[o];
    rgy[i] = gy[o];
  }
  if (mode == 0) {
#pragma unroll
    for (int i = 0; i < L_; ++i)
      hls[i] = lsloc[(size_t)(kv + i) * B_ + b];   // local rows, coalesced
  }
  int jmap[L_];
#pragma unroll
  for (int i = 0; i < L_; ++i) jmap[i] = map[kv + i];     // block-uniform
  uint2 sraw, traw;
  if (wmode == 2) {
    if (c > 0)
      sraw = *(const uint2*)&Sread[((size_t)c * B_ + b) * 8];
    if (c < C_ - 1)
      traw = *(const uint2*)&Tread[((size_t)(c + 1) * B_ + b) * 8];
  }

  // ---- convert valid gamma (gvx kept: needed for extrinsic) ----
  float gvx[L_];
  float gc[L_][4];
#pragma unroll
  for (int i = 0; i < L_; ++i) {
    gvx[i] = __half2float(hgx[i]);
    gam_lin(gvx[i], b2f(rgy[i]), gc[i]);
  }

  // ---------------- forward ----------------
  float a[8];
  if (c == 0) {
    a[0] = 1.0f;
#pragma unroll
    for (int s = 1; s < 8; ++s) a[s] = 0.0f;
  } else if (wmode == 0) {
    int wu = kv < W0_ ? kv : W0_;
    if (kv <= W0_) {                 // warmup reaches position 0: exact init
      a[0] = 1.0f;
#pragma unroll
      for (int s = 1; s < 8; ++s) a[s] = 0.0f;
    } else {
#pragma unroll
      for (int s = 0; s < 8; ++s) a[s] = 1.0f;
    }
    int n = wu, k = kv - wu;
    __half cx0, cx1;
    unsigned short cy0, cy1;
    if (n > 0) {
      size_t o0 = (size_t)k * B_ + b, o1 = (size_t)(k + 1) * B_ + b;
      cx0 = gx[o0]; cy0 = gy[o0]; cx1 = gx[o1]; cy1 = gy[o1];
    }
    while (n > 0) {
      __half nx0, nx1;
      unsigned short ny0, ny1;
      if (n > 2) {
        size_t o0 = (size_t)(k + 2) * B_ + b, o1 = (size_t)(k + 3) * B_ + b;
        nx0 = gx[o0]; ny0 = gy[o0]; nx1 = gx[o1]; ny1 = gy[o1];
      }
      float g[4];
      gam_lin(__half2float(cx0), b2f(cy0), g); step_fwd_lin(a, g);
      gam_lin(__half2float(cx1), b2f(cy1), g); step_fwd_lin(a, g);
      renorm_lin(a);
      if (n > 2) { cx0 = nx0; cy0 = ny0; cx1 = nx1; cy1 = ny1; }
      k += 2; n -= 2;
    }
  } else {
    unpack8_log8(sraw, a);           // pure inheritance (c>0 here)
  }
  // valid region: record alpha, then step (all L steps -> a = alpha(kend))
  float a2d[L_][8];
#pragma unroll
  for (int i = 0; i < L_; ++i) {
#pragma unroll
    for (int s = 0; s < 8; ++s) a2d[i][s] = a[s];
    step_fwd_lin(a, gc[i]);
    if (i & 1) renorm_lin(a);
  }
  if (wrS)
    store8_log8(&Swrite[((size_t)(c + 1) * B_ + b) * 8], a);

  // ---------------- backward + posterior ----------------
  float bt[8];
  if (c == C_ - 1) {
#pragma unroll
    for (int s = 0; s < 8; ++s) bt[s] = 1.0f;    // exact tail init (uniform)
  } else if (wmode == 0) {
    int rem = K_ - kend;
    int wub = rem < W0_ ? rem : W0_;
#pragma unroll
    for (int s = 0; s < 8; ++s) bt[s] = 1.0f;
    int n = wub, k = kend + wub - 1;
    __half cx0, cx1;
    unsigned short cy0, cy1;
    if (n > 0) {
      size_t o0 = (size_t)k * B_ + b, o1 = (size_t)(k - 1) * B_ + b;
      cx0 = gx[o0]; cy0 = gy[o0]; cx1 = gx[o1]; cy1 = gy[o1];
    }
    while (n > 0) {
      __half nx0, nx1;
      unsigned short ny0, ny1;
      if (n > 2) {
        size_t o0 = (size_t)(k - 2) * B_ + b, o1 = (size_t)(k - 3) * B_ + b;
        nx0 = gx[o0]; ny0 = gy[o0]; nx1 = gx[o1]; ny1 = gy[o1];
      }
      float g[4];
      gam_lin(__half2float(cx0), b2f(cy0), g); step_bwd_lin(bt, g);
      gam_lin(__half2float(cx1), b2f(cy1), g); step_bwd_lin(bt, g);
      renorm_lin(bt);
      if (n > 2) { cx0 = nx0; cy0 = ny0; cx1 = nx1; cy1 = ny1; }
      k -= 2; n -= 2;
    }
  } else {
    unpack8_log8(traw, bt);          // pure inheritance (c<C_-1 here)
  }
  // valid region, descending: posterior + extrinsic + beta step
#pragma unroll
  for (int ii = 0; ii < L_; ++ii) {
    const int i = L_ - 1 - ii;
    const float* g = gc[i];
    float s00 = 0.0f, s01 = 0.0f, s10 = 0.0f, s11 = 0.0f;
    float bn[8];
#pragma unroll
    for (int s = 0; s < 8; ++s) {
      const int s0 = s & 1, s1b = (s >> 1) & 1, s2b = (s >> 2) & 1;
      const int f0 = s1b ^ s0, q = s1b ^ s2b;
      float b0 = bt[(f0 << 2) | (s >> 1)];
      float b1 = bt[((f0 ^ 1) << 2) | (s >> 1)];
      float m0 = a2d[i][s] * b0;
      float m1 = a2d[i][s] * b1;
      if (q == 0) { s00 += m0; s10 += m1; } else { s01 += m0; s11 += m1; }
      bn[s] = g[q] * b0 + g[2 + (q ^ 1)] * b1;
    }
    float t0 = g[0] * s00 + g[1] * s01;
    float t1 = g[3] * s10 + g[2] * s11;
    float lpost = LOG2F(fmaxf(t0, 1e-37f)) - LOG2F(fmaxf(t1, 1e-37f));
    const size_t oo = (size_t)jmap[i] * B_ + b;
    if (mode == 0) {
      float le = lpost - gvx[i];               // lpost - (ls + la)
      gxother[oo] = __float2half(__half2float(hls[i]) + le);
    } else {
      lpost_out[oo] = -LN2 * lpost;            // final output value, row perm[kk]
    }
#pragma unroll
    for (int s = 0; s < 8; ++s) bt[s] = bn[s];
    if (ii & 1) renorm_lin(bt);
  }
  if (wrS)
    store8_log8(&Twrite[((size_t)c * B_ + b) * 8], bt);
}

// ---------------- prep: de-interleave + transpose + scale to log2 domain --
// (no gx1 store: at it0, la=0 so gx1 content == ls1; the it0 phase-0 launch
// passes ls1 as its gx plane, and gx1 is first written by it0 phase-1.)
__global__ __launch_bounds__(256) void k_prep1(const float* __restrict__ inp,
                                               __half* __restrict__ ls1,
                                               unsigned short* __restrict__ gy1,
                                               unsigned short* __restrict__ gy2) {
  __shared__ float t[3][64][65];
  const int tid = threadIdx.x;
  const int k0 = blockIdx.x * 64, b0 = blockIdx.y * 64;
  const int tk = tid & 63, tq = tid >> 6;
  for (int bb = tq; bb < 64; bb += 4) {
    size_t base = (size_t)(b0 + bb) * (3 * K_) + 3 * (size_t)(k0 + tk);
    t[0][bb][tk] = inp[base + 0];
    t[1][bb][tk] = inp[base + 1];
    t[2][bb][tk] = inp[base + 2];
  }
  __syncthreads();
  const int tb = tid & 63, kq = tid >> 6;
  for (int kk = kq; kk < 64; kk += 4) {
    size_t o = (size_t)(k0 + kk) * B_ + (b0 + tb);
    float sv = -LOG2E * t[0][tb][kk];
    float p1 = -LOG2E * t[1][tb][kk];
    float p2 = -LOG2E * t[2][tb][kk];
    ls1[o] = __float2half(sv);
    gy1[o] = f2b(p1);
    gy2[o] = f2b(p2);
  }
}

// 4 rows per block to amortize launch width
__global__ __launch_bounds__(256) void k_prep2(const __half* __restrict__ ls1,
                                               const int* __restrict__ perm,
                                               __half* __restrict__ ls2,
                                               int* __restrict__ inv) {
  const int b = threadIdx.x;
#pragma unroll
  for (int r = 0; r < 4; ++r) {
    const int j = blockIdx.x * 4 + r;
    const int p = perm[j];
    ls2[(size_t)j * B_ + b] = ls1[(size_t)p * B_ + b];
    if (b == 0) inv[p] = j;
  }
}

// ---------------- output: out[b,i] = lpostT[i, b] (plain transpose) -------
__global__ __launch_bounds__(256) void k_out(const float* __restrict__ lpostT,
                                             float* __restrict__ out) {
  __shared__ float t[64][65];
  const int tid = threadIdx.x;
  const int i0 = blockIdx.x * 64, b0 = blockIdx.y * 64;
  const int tb = tid & 63, iq = tid >> 6;
  for (int ii = iq; ii < 64; ii += 4) {
    t[ii][tb] = lpostT[(size_t)(i0 + ii) * B_ + (b0 + tb)];
  }
  __syncthreads();
  const int ik = tid & 63, bq = tid >> 6;
  for (int bb = bq; bb < 64; bb += 4) {
    out[(size_t)(b0 + bb) * K_ + (i0 + ik)] = t[ik][bb];
  }
}

// ---------------- launch ---------------------------------------------------
extern "C" void kernel_launch(void* const* d_in, const int* in_sizes, int n_in,
                              void* d_out, int out_size, void* d_ws, size_t ws_size,
                              hipStream_t stream) {
  (void)in_sizes; (void)n_in; (void)out_size; (void)ws_size;
  const float* inp = (const float*)d_in[0];
  const int* perm = (const int*)d_in[1];
  float* out = (float*)d_out;

  char* ws = (char*)d_ws;
  const size_t KB = (size_t)K_ * B_;     // elements per [K][B] plane
  const size_t PB = KB * 4;              // bytes per f32 plane
  const size_t PH = KB * 2;              // bytes per 16-bit plane
  float*  lpostT  = (float*)(ws);
  __half* gx1     = (__half*)(ws + PB);
  __half* gx2     = (__half*)(ws + PB + PH);
  unsigned short* gy1 = (unsigned short*)(ws + PB + PH * 2);
  unsigned short* gy2 = (unsigned short*)(ws + PB + PH * 3);
  __half* ls1     = (__half*)(ws + PB + PH * 4);
  __half* ls2     = (__half*)(ws + PB + PH * 5);
  int*    inv     = (int*)(ws + PB + PH * 6);          // K ints
  // NII boundary-state buffers: [C_+1][B][8] u8 (log8), ping-pong
  const size_t SB = (size_t)(C_ + 1) * B_ * 8;         // ~2.1 MB each
  char* nb = ws + PB + PH * 6 + 65536;
  unsigned char* S1[2] = {(unsigned char*)(nb),          (unsigned char*)(nb + SB)};
  unsigned char* T1[2] = {(unsigned char*)(nb + SB * 2), (unsigned char*)(nb + SB * 3)};
  unsigned char* S2[2] = {(unsigned char*)(nb + SB * 4), (unsigned char*)(nb + SB * 5)};
  unsigned char* T2[2] = {(unsigned char*)(nb + SB * 6), (unsigned char*)(nb + SB * 7)};
  // total: 6.3 + 6*3.15 + 8*2.1 MB ~= 42 MB (L3-resident)

  k_prep1<<<dim3(K_ / 64, B_ / 64), 256, 0, stream>>>(inp, ls1, gy1, gy2);
  k_prep2<<<K_ / 4, 256, 0, stream>>>(ls1, perm, ls2, inv);

  for (int it = 0; it < NITER; ++it) {
    const int pr = it & 1, pw = pr ^ 1;   // read prev-iter buffer, write other
    const int wm = (it == 0) ? 0 : 2;
    const int wrS = (it != NITER - 1) ? 1 : 0;
    // phase 0 (decoder 1): extrinsic -> gx2[inv[kk]]; local ls plane = ls1.
    // At it0, gx1 is uninitialized but bit-equal to ls1 (la=0): pass ls1.
    const __half* g1 = (it == 0) ? ls1 : gx1;
    k_half<<<C_, 256, 0, stream>>>(g1, gy1, ls1, inv, gx2, lpostT,
                                   S1[pr], S1[pw], T1[pr], T1[pw],
                                   wm, 0, wrS);
    // phase 1 (decoder 2): extrinsic -> gx1[perm[kk]]; local ls plane = ls2
    k_half<<<C_, 256, 0, stream>>>(gx2, gy2, ls2, perm, gx1, lpostT,
                                   S2[pr], S2[pw], T2[pr], T2[pw],
                                   wm, (it == NITER - 1) ? 1 : 0, wrS);
  }
  k_out<<<dim3(K_ / 64, B_ / 64), 256, 0, stream>>>(lpostT, out);
}

// Round 18
// 199.253 us; speedup vs baseline: 1.3636x; 1.0486x over previous
//
#include <hip/hip_runtime.h>
#include <hip/hip_fp16.h>

// ---------------- problem constants ----------------
constexpr int B_ = 256;        // batch
constexpr int K_ = 6144;       // block length
constexpr int NITER = 6;
constexpr int L_ = 6;          // window valid length -> C_=1024 = 4 blocks/CU
constexpr int W0_ = 6;         // uniform-init warmup (iteration 0); == L_ so
                               // wu is uniform across chunks and fully MLP'd
constexpr int C_ = K_ / L_;    // chunks = 1024
constexpr float LOG2E = 1.4426950408889634f;
constexpr float LN2   = 0.6931471805599453f;

static_assert(K_ % L_ == 0, "");
static_assert((L_ % 2) == 0 && (W0_ % 2) == 0, "");
static_assert(W0_ <= L_, "uniform-warmup trick requires W0 <= L");

#if __has_builtin(__builtin_amdgcn_exp2f)
#define EXP2F(x) __builtin_amdgcn_exp2f(x)
#else
#define EXP2F(x) exp2f(x)
#endif
#if __has_builtin(__builtin_amdgcn_logf)
#define LOG2F(x) __builtin_amdgcn_logf(x)
#else
#define LOG2F(x) log2f(x)
#endif
#if __has_builtin(__builtin_amdgcn_rcpf)
#define RCPF(x) __builtin_amdgcn_rcpf(x)
#else
#define RCPF(x) (1.0f / (x))
#endif

// ---- bf16 scalar helpers (RNE) ----
__device__ __forceinline__ float b2f(unsigned short u) {
  return __uint_as_float((unsigned)u << 16);
}
__device__ __forceinline__ unsigned short f2b(float f) {
  unsigned u = __float_as_uint(f);
  u += 0x7FFFu + ((u >> 16) & 1u);
  return (unsigned short)(u >> 16);
}

// trellis: fb(s,u)=u^s1^s0, nxt(s,u)=(fb<<2)|(s>>1), par(s,u)=u^s1^s2
// Linear-domain with normalized gammas: ghat[u][p] = A_u*B_p, A={1,es} by
// sign of gx (es=2^-|gx|), B likewise (ep=2^-|gy|). Common scale cancels in
// the posterior ratio and renormalized alpha/beta -> equivalent to log-MAP.

__device__ __forceinline__ void gam_lin(float gxv, float gyv, float g[4]) {
  float es = EXP2F(-fabsf(gxv));
  float ep = EXP2F(-fabsf(gyv));
  float fu0 = gxv >= 0.0f ? 1.0f : es;
  float fu1 = gxv >= 0.0f ? es : 1.0f;
  float fp0 = gyv >= 0.0f ? 1.0f : ep;
  float fp1 = gyv >= 0.0f ? ep : 1.0f;
  g[0] = fu0 * fp0; g[1] = fu0 * fp1;
  g[2] = fu1 * fp0; g[3] = fu1 * fp1;
}

__device__ __forceinline__ void step_fwd_lin(float a[8], const float g[4]) {
  float an[8];
#pragma unroll
  for (int sn = 0; sn < 8; ++sn) {
    const int u0 = ((sn >> 2) ^ (sn & 1)) & 1;
    const int p0 = ((sn >> 2) ^ ((sn >> 1) & 1)) & 1;
    an[sn] = a[(sn & 3) * 2] * g[u0 * 2 + p0]
           + a[(sn & 3) * 2 + 1] * g[(u0 ^ 1) * 2 + (p0 ^ 1)];
  }
#pragma unroll
  for (int s = 0; s < 8; ++s) a[s] = an[s];
}

__device__ __forceinline__ void step_bwd_lin(float bt[8], const float g[4]) {
  float bn[8];
#pragma unroll
  for (int s = 0; s < 8; ++s) {
    const int s0 = s & 1, s1b = (s >> 1) & 1, s2b = (s >> 2) & 1;
    const int f0 = s1b ^ s0, q = s1b ^ s2b;
    bn[s] = g[q] * bt[(f0 << 2) | (s >> 1)]
          + g[2 + (q ^ 1)] * bt[((f0 ^ 1) << 2) | (s >> 1)];
  }
#pragma unroll
  for (int s = 0; s < 8; ++s) bt[s] = bn[s];
}

// max-renorm with tiny floor injection: NaN/underflow-proof
__device__ __forceinline__ void renorm_lin(float a[8]) {
  float m = fmaxf(fmaxf(fmaxf(a[0], a[1]), fmaxf(a[2], a[3])),
                  fmaxf(fmaxf(a[4], a[5]), fmaxf(a[6], a[7])));
  float r = RCPF(fmaxf(m, 1e-30f));
#pragma unroll
  for (int s = 0; s < 8; ++s) a[s] = fmaf(a[s], r, 1e-32f);
}

// ---- log8-packed boundary states: u8 = round(-16*log2(x)), clamp 255.
// States are renormalized probs in (1e-32, 1]; values below 2^-15.9 clamp
// up (dead components, contribute <=2e-5 to lpost). Max rel error 2.2%. ----
__device__ __forceinline__ void store8_log8(unsigned char* p, const float a[8]) {
  unsigned int us[8];
#pragma unroll
  for (int s = 0; s < 8; ++s) {
    float l = -16.0f * LOG2F(a[s]);
    l = fminf(l, 255.0f);
    us[s] = (unsigned int)(l + 0.5f);
  }
  uint2 v;
  v.x = us[0] | (us[1] << 8) | (us[2] << 16) | (us[3] << 24);
  v.y = us[4] | (us[5] << 8) | (us[6] << 16) | (us[7] << 24);
  *(uint2*)p = v;
}

__device__ __forceinline__ void unpack8_log8(uint2 v, float a[8]) {
#pragma unroll
  for (int s = 0; s < 4; ++s)
    a[s] = EXP2F(-0.0625f * (float)((v.x >> (8 * s)) & 0xFFu));
#pragma unroll
  for (int s = 0; s < 4; ++s)
    a[4 + s] = EXP2F(-0.0625f * (float)((v.y >> (8 * s)) & 0xFFu));
}

// ---------------- k_half: one windowed BCJR half-iteration (linear) -------
// 256-thread blocks = 4 waves = the 4 b-quarters of ONE chunk.
// gx planes fp16; gy planes bf16; ls planes fp16; boundary states log8.
// Permutation identity: lsother[map[kk]] == lsloc[kk], so the extrinsic
// uses the LOCAL ls plane (coalesced, no random gather). At it0 the caller
// passes lsloc AS gx (bit-identical: la=0).
// wmode 0: uniform warmup, exactly W0_ steps (kv >= W0_ for all c >= 1),
//          all warmup gammas loaded upfront (full MLP, no pipeline chain).
// wmode 2: pure inheritance from prev-iteration boundary states (it>=1).
// mode 0: scatter extrinsic into other decoder's gx at row map[kk].
// mode 1: write -ln2*lpost at ORIGINAL-domain row map[kk]=perm[kk] ->
//         k_out becomes a plain transpose-copy.
// wrS 0: skip dead boundary-state stores (last iteration).
__global__ __launch_bounds__(256, 4) void k_half(const __half* __restrict__ gx,
                                                 const unsigned short* __restrict__ gy,
                                                 const __half* __restrict__ lsloc,
                                                 const int* __restrict__ map,
                                                 __half* __restrict__ gxother,
                                                 float* __restrict__ lpost_out,
                                                 const unsigned char* __restrict__ Sread,
                                                 unsigned char* __restrict__ Swrite,
                                                 const unsigned char* __restrict__ Tread,
                                                 unsigned char* __restrict__ Twrite,
                                                 int wmode, int mode, int wrS) {
  const int tid = threadIdx.x;
  const int c = blockIdx.x;                      // one chunk per block
  const int b = tid;                             // wave = b-quarter
  const int kv = c * L_;
  const int kend = kv + L_;

  // ---- issue ALL independent loads upfront ----
  __half hgx[L_];
  unsigned short rgy[L_];
  __half hls[L_];
#pragma unroll
  for (int i = 0; i < L_; ++i) {
    size_t o = (size_t)(kv + i) * B_ + b;
    hgx[i] = gx[o];
    rgy[i] = gy[o];
  }
  if (mode == 0) {
#pragma unroll
    for (int i = 0; i < L_; ++i)
      hls[i] = lsloc[(size_t)(kv + i) * B_ + b];   // local rows, coalesced
  }
  int jmap[L_];
#pragma unroll
  for (int i = 0; i < L_; ++i) jmap[i] = map[kv + i];     // block-uniform
  uint2 sraw, traw;
  __half wfx[W0_], wbx[W0_];
  unsigned short wfy[W0_], wby[W0_];
  if (wmode == 2) {
    if (c > 0)
      sraw = *(const uint2*)&Sread[((size_t)c * B_ + b) * 8];
    if (c < C_ - 1)
      traw = *(const uint2*)&Tread[((size_t)(c + 1) * B_ + b) * 8];
  } else {
    // warmup gammas, all upfront (wu == W0_ exactly, since kv >= W0_ at c>=1)
    if (c > 0) {
#pragma unroll
      for (int q = 0; q < W0_; ++q) {
        size_t o = (size_t)(kv - W0_ + q) * B_ + b;
        wfx[q] = gx[o]; wfy[q] = gy[o];
      }
    }
    if (c < C_ - 1) {
#pragma unroll
      for (int q = 0; q < W0_; ++q) {
        size_t o = (size_t)(kend + W0_ - 1 - q) * B_ + b;
        wbx[q] = gx[o]; wby[q] = gy[o];
      }
    }
  }

  // ---- convert valid gamma (gvx kept: needed for extrinsic) ----
  float gvx[L_];
  float gc[L_][4];
#pragma unroll
  for (int i = 0; i < L_; ++i) {
    gvx[i] = __half2float(hgx[i]);
    gam_lin(gvx[i], b2f(rgy[i]), gc[i]);
  }

  // ---------------- forward ----------------
  float a[8];
  if (c == 0) {
    a[0] = 1.0f;
#pragma unroll
    for (int s = 1; s < 8; ++s) a[s] = 0.0f;
  } else if (wmode == 0) {
    if (c == 1) {                    // warmup starts at position 0: exact init
      a[0] = 1.0f;
#pragma unroll
      for (int s = 1; s < 8; ++s) a[s] = 0.0f;
    } else {
#pragma unroll
      for (int s = 0; s < 8; ++s) a[s] = 1.0f;
    }
#pragma unroll
    for (int q = 0; q < W0_; ++q) {
      float g[4];
      gam_lin(__half2float(wfx[q]), b2f(wfy[q]), g);
      step_fwd_lin(a, g);
      if (q & 1) renorm_lin(a);
    }
  } else {
    unpack8_log8(sraw, a);           // pure inheritance (c>0 here)
  }
  // valid region: record alpha, then step (all L steps -> a = alpha(kend))
  float a2d[L_][8];
#pragma unroll
  for (int i = 0; i < L_; ++i) {
#pragma unroll
    for (int s = 0; s < 8; ++s) a2d[i][s] = a[s];
    step_fwd_lin(a, gc[i]);
    if (i & 1) renorm_lin(a);
  }
  if (wrS)
    store8_log8(&Swrite[((size_t)(c + 1) * B_ + b) * 8], a);

  // ---------------- backward + posterior ----------------
  float bt[8];
  if (c == C_ - 1) {
#pragma unroll
    for (int s = 0; s < 8; ++s) bt[s] = 1.0f;    // exact tail init (uniform)
  } else if (wmode == 0) {
#pragma unroll
    for (int s = 0; s < 8; ++s) bt[s] = 1.0f;    // uniform (exact at c=C_-2)
#pragma unroll
    for (int q = 0; q < W0_; ++q) {
      float g[4];
      gam_lin(__half2float(wbx[q]), b2f(wby[q]), g);
      step_bwd_lin(bt, g);
      if (q & 1) renorm_lin(bt);
    }
  } else {
    unpack8_log8(traw, bt);          // pure inheritance (c<C_-1 here)
  }
  // valid region, descending: posterior + extrinsic + beta step
#pragma unroll
  for (int ii = 0; ii < L_; ++ii) {
    const int i = L_ - 1 - ii;
    const float* g = gc[i];
    float s00 = 0.0f, s01 = 0.0f, s10 = 0.0f, s11 = 0.0f;
    float bn[8];
#pragma unroll
    for (int s = 0; s < 8; ++s) {
      const int s0 = s & 1, s1b = (s >> 1) & 1, s2b = (s >> 2) & 1;
      const int f0 = s1b ^ s0, q = s1b ^ s2b;
      float b0 = bt[(f0 << 2) | (s >> 1)];
      float b1 = bt[((f0 ^ 1) << 2) | (s >> 1)];
      float m0 = a2d[i][s] * b0;
      float m1 = a2d[i][s] * b1;
      if (q == 0) { s00 += m0; s10 += m1; } else { s01 += m0; s11 += m1; }
      bn[s] = g[q] * b0 + g[2 + (q ^ 1)] * b1;
    }
    float t0 = g[0] * s00 + g[1] * s01;
    float t1 = g[3] * s10 + g[2] * s11;
    float lpost = LOG2F(fmaxf(t0, 1e-37f)) - LOG2F(fmaxf(t1, 1e-37f));
    const size_t oo = (size_t)jmap[i] * B_ + b;
    if (mode == 0) {
      float le = lpost - gvx[i];               // lpost - (ls + la)
      gxother[oo] = __float2half(__half2float(hls[i]) + le);
    } else {
      lpost_out[oo] = -LN2 * lpost;            // final output value, row perm[kk]
    }
#pragma unroll
    for (int s = 0; s < 8; ++s) bt[s] = bn[s];
    if (ii & 1) renorm_lin(bt);
  }
  if (wrS)
    store8_log8(&Twrite[((size_t)c * B_ + b) * 8], bt);
}

// ---------------- prep: de-interleave + transpose + scale to log2 domain --
// (no gx1 store: at it0, la=0 so gx1 content == ls1; the it0 phase-0 launch
// passes ls1 as its gx plane, and gx1 is first written by it0 phase-1.)
__global__ __launch_bounds__(256) void k_prep1(const float* __restrict__ inp,
                                               __half* __restrict__ ls1,
                                               unsigned short* __restrict__ gy1,
                                               unsigned short* __restrict__ gy2) {
  __shared__ float t[3][64][65];
  const int tid = threadIdx.x;
  const int k0 = blockIdx.x * 64, b0 = blockIdx.y * 64;
  const int tk = tid & 63, tq = tid >> 6;
  for (int bb = tq; bb < 64; bb += 4) {
    size_t base = (size_t)(b0 + bb) * (3 * K_) + 3 * (size_t)(k0 + tk);
    t[0][bb][tk] = inp[base + 0];
    t[1][bb][tk] = inp[base + 1];
    t[2][bb][tk] = inp[base + 2];
  }
  __syncthreads();
  const int tb = tid & 63, kq = tid >> 6;
  for (int kk = kq; kk < 64; kk += 4) {
    size_t o = (size_t)(k0 + kk) * B_ + (b0 + tb);
    float sv = -LOG2E * t[0][tb][kk];
    float p1 = -LOG2E * t[1][tb][kk];
    float p2 = -LOG2E * t[2][tb][kk];
    ls1[o] = __float2half(sv);
    gy1[o] = f2b(p1);
    gy2[o] = f2b(p2);
  }
}

// 8 rows per block to amortize launch width
__global__ __launch_bounds__(256) void k_prep2(const __half* __restrict__ ls1,
                                               const int* __restrict__ perm,
                                               __half* __restrict__ ls2,
                                               int* __restrict__ inv) {
  const int b = threadIdx.x;
#pragma unroll
  for (int r = 0; r < 8; ++r) {
    const int j = blockIdx.x * 8 + r;
    const int p = perm[j];
    ls2[(size_t)j * B_ + b] = ls1[(size_t)p * B_ + b];
    if (b == 0) inv[p] = j;
  }
}

// ---------------- output: out[b,i] = lpostT[i, b] (plain transpose) -------
__global__ __launch_bounds__(256) void k_out(const float* __restrict__ lpostT,
                                             float* __restrict__ out) {
  __shared__ float t[64][65];
  const int tid = threadIdx.x;
  const int i0 = blockIdx.x * 64, b0 = blockIdx.y * 64;
  const int tb = tid & 63, iq = tid >> 6;
  for (int ii = iq; ii < 64; ii += 4) {
    t[ii][tb] = lpostT[(size_t)(i0 + ii) * B_ + (b0 + tb)];
  }
  __syncthreads();
  const int ik = tid & 63, bq = tid >> 6;
  for (int bb = bq; bb < 64; bb += 4) {
    out[(size_t)(b0 + bb) * K_ + (i0 + ik)] = t[ik][bb];
  }
}

// ---------------- launch ---------------------------------------------------
extern "C" void kernel_launch(void* const* d_in, const int* in_sizes, int n_in,
                              void* d_out, int out_size, void* d_ws, size_t ws_size,
                              hipStream_t stream) {
  (void)in_sizes; (void)n_in; (void)out_size; (void)ws_size;
  const float* inp = (const float*)d_in[0];
  const int* perm = (const int*)d_in[1];
  float* out = (float*)d_out;

  char* ws = (char*)d_ws;
  const size_t KB = (size_t)K_ * B_;     // elements per [K][B] plane
  const size_t PB = KB * 4;              // bytes per f32 plane
  const size_t PH = KB * 2;              // bytes per 16-bit plane
  float*  lpostT  = (float*)(ws);
  __half* gx1     = (__half*)(ws + PB);
  __half* gx2     = (__half*)(ws + PB + PH);
  unsigned short* gy1 = (unsigned short*)(ws + PB + PH * 2);
  unsigned short* gy2 = (unsigned short*)(ws + PB + PH * 3);
  __half* ls1     = (__half*)(ws + PB + PH * 4);
  __half* ls2     = (__half*)(ws + PB + PH * 5);
  int*    inv     = (int*)(ws + PB + PH * 6);          // K ints
  // NII boundary-state buffers: [C_+1][B][8] u8 (log8), ping-pong
  const size_t SB = (size_t)(C_ + 1) * B_ * 8;         // ~2.1 MB each
  char* nb = ws + PB + PH * 6 + 65536;
  unsigned char* S1[2] = {(unsigned char*)(nb),          (unsigned char*)(nb + SB)};
  unsigned char* T1[2] = {(unsigned char*)(nb + SB * 2), (unsigned char*)(nb + SB * 3)};
  unsigned char* S2[2] = {(unsigned char*)(nb + SB * 4), (unsigned char*)(nb + SB * 5)};
  unsigned char* T2[2] = {(unsigned char*)(nb + SB * 6), (unsigned char*)(nb + SB * 7)};
  // total: 6.3 + 6*3.15 + 8*2.1 MB ~= 42 MB (L3-resident)

  k_prep1<<<dim3(K_ / 64, B_ / 64), 256, 0, stream>>>(inp, ls1, gy1, gy2);
  k_prep2<<<K_ / 8, 256, 0, stream>>>(ls1, perm, ls2, inv);

  for (int it = 0; it < NITER; ++it) {
    const int pr = it & 1, pw = pr ^ 1;   // read prev-iter buffer, write other
    const int wm = (it == 0) ? 0 : 2;
    const int wrS = (it != NITER - 1) ? 1 : 0;
    // phase 0 (decoder 1): extrinsic -> gx2[inv[kk]]; local ls plane = ls1.
    // At it0, gx1 is uninitialized but bit-equal to ls1 (la=0): pass ls1.
    const __half* g1 = (it == 0) ? ls1 : gx1;
    k_half<<<C_, 256, 0, stream>>>(g1, gy1, ls1, inv, gx2, lpostT,
                                   S1[pr], S1[pw], T1[pr], T1[pw],
                                   wm, 0, wrS);
    // phase 1 (decoder 2): extrinsic -> gx1[perm[kk]]; local ls plane = ls2
    k_half<<<C_, 256, 0, stream>>>(gx2, gy2, ls2, perm, gx1, lpostT,
                                   S2[pr], S2[pw], T2[pr], T2[pw],
                                   wm, (it == NITER - 1) ? 1 : 0, wrS);
  }
  k_out<<<dim3(K_ / 64, B_ / 64), 256, 0, stream>>>(lpostT, out);
}